// Round 1
// baseline (959.649 us; speedup 1.0000x reference)
//
#include <hip/hip_runtime.h>
#include <hip/hip_bf16.h>

#define NN 2048
#define DD 128
#define HH 8
#define HDIM 16
#define LL 8
#define GG 16
#define BNEPS 1e-5f

typedef unsigned int u32;
typedef unsigned long long u64;

// ---------------- adjacency build ----------------
__global__ __launch_bounds__(256) void scatter_k(const int* __restrict__ ei, u32* __restrict__ A, int E) {
    int e = blockIdx.x * 256 + threadIdx.x;
    if (e < E) {
        int s = ei[e];
        int d = ei[E + e];
        atomicAdd(&A[s * NN + d], 1u);
    }
}

__global__ __launch_bounds__(256) void count_k(const u32* __restrict__ A, u32* __restrict__ deg) {
    int r = blockIdx.x, t = threadIdx.x;
    __shared__ u32 sb[256];
    u32 c = 0;
    for (int j = t; j < NN; j += 256) c += (A[r * NN + j] != 0u) ? 1u : 0u;
    sb[t] = c; __syncthreads();
    for (int off = 128; off; off >>= 1) { if (t < off) sb[t] += sb[t + off]; __syncthreads(); }
    if (t == 0) deg[r] = sb[0];
}

__global__ __launch_bounds__(256) void scan_k(const u32* __restrict__ deg, u32* __restrict__ rowptr) {
    __shared__ u32 part[256];
    int t = threadIdx.x;
    u32 loc[8]; u32 s = 0;
#pragma unroll
    for (int i = 0; i < 8; i++) { loc[i] = deg[t * 8 + i]; s += loc[i]; }
    part[t] = s; __syncthreads();
    for (int off = 1; off < 256; off <<= 1) {
        u32 vprev = (t >= off) ? part[t - off] : 0u;
        __syncthreads();
        part[t] += vprev;
        __syncthreads();
    }
    u32 run = (t == 0) ? 0u : part[t - 1];
    if (t == 0) rowptr[0] = 0u;
#pragma unroll
    for (int i = 0; i < 8; i++) { run += loc[i]; rowptr[t * 8 + i + 1] = run; }
}

// ordered compaction of one dense-A row into CSR (col order preserved)
__global__ __launch_bounds__(256) void emit_k(const u32* __restrict__ A, const u32* __restrict__ rowptr,
                                              u32* __restrict__ colidx, u32* __restrict__ cntv) {
    int r = blockIdx.x, tid = threadIdx.x;
    int lane = tid & 63, wid = tid >> 6;
    __shared__ u32 wsum[4];
    u32 base = rowptr[r];
    u32 cb = 0;
    for (int c0 = 0; c0 < NN; c0 += 256) {
        int c = c0 + tid;
        u32 a = A[r * NN + c];
        bool p = (a != 0u);
        u64 bal = __ballot(p);
        u32 rankw = (u32)__popcll(bal & ((1ull << lane) - 1ull));
        if (lane == 0) wsum[wid] = (u32)__popcll(bal);
        __syncthreads();
        u32 woff = 0;
#pragma unroll
        for (int w2 = 0; w2 < 4; w2++) if (w2 < wid) woff += wsum[w2];
        u32 tot = wsum[0] + wsum[1] + wsum[2] + wsum[3];
        if (p) { u32 pos = base + cb + woff + rankw; colidx[pos] = (u32)c; cntv[pos] = a; }
        cb += tot;
        __syncthreads();
    }
}

// ---------------- input projection ----------------
__global__ __launch_bounds__(256) void h0_k(const float* __restrict__ X, const float* __restrict__ pe,
                                            const float* __restrict__ pW, const float* __restrict__ pb,
                                            const float* __restrict__ peW, const float* __restrict__ peb,
                                            float* __restrict__ h) {
    int idx = blockIdx.x * 256 + threadIdx.x;
    int r = idx >> 7, d = idx & 127;
    float acc = pb[d] + peb[d];
    acc += X[r * 4 + 0] * pW[0 * DD + d];
    acc += X[r * 4 + 1] * pW[1 * DD + d];
    acc += X[r * 4 + 2] * pW[2 * DD + d];
    acc += X[r * 4 + 3] * pW[3 * DD + d];
    acc += pe[r * 2 + 0] * peW[0 * DD + d];
    acc += pe[r * 2 + 1] * peW[1 * DD + d];
    h[idx] = acc;
}

// ---------------- GEMMs ----------------
// block: 256 threads = 32 col-threads (x4 cols) * 8 row-threads. grid: (M/8, NT/128)
__global__ __launch_bounds__(256) void qkv_k(const float* __restrict__ h,
                                             const float* __restrict__ Wq, const float* __restrict__ bq,
                                             const float* __restrict__ Wk, const float* __restrict__ bk,
                                             const float* __restrict__ Wv, const float* __restrict__ bv,
                                             float* __restrict__ q, float* __restrict__ k, float* __restrict__ v) {
    int z = blockIdx.z;
    const float* W = (z == 0) ? Wq : ((z == 1) ? Wk : Wv);
    const float* bias = (z == 0) ? bq : ((z == 1) ? bk : bv);
    float* out = (z == 0) ? q : ((z == 1) ? k : v);
    float scale = (z == 0) ? 0.25f : 1.0f;
    int tn = threadIdx.x & 31, tm = threadIdx.x >> 5;
    int m = blockIdx.x * 8 + tm;
    int nc = tn * 4;
    const float* ar = h + m * DD;
    float ax = 0, ay = 0, az = 0, aw = 0;
#pragma unroll 16
    for (int kk = 0; kk < DD; kk++) {
        float a = ar[kk];
        float4 b = *(const float4*)(W + kk * DD + nc);
        ax += a * b.x; ay += a * b.y; az += a * b.z; aw += a * b.w;
    }
    float4 bb = *(const float4*)(bias + nc);
    ax = (ax + bb.x) * scale; ay = (ay + bb.y) * scale;
    az = (az + bb.z) * scale; aw = (aw + bb.w) * scale;
    *(float4*)(out + m * DD + nc) = make_float4(ax, ay, az, aw);
}

template <int K, int NT, bool RELU, bool RES>
__global__ __launch_bounds__(256) void gemm_k(const float* __restrict__ A, const float* __restrict__ B,
                                              const float* __restrict__ bias, const float* __restrict__ res,
                                              float* __restrict__ C) {
    int tn = threadIdx.x & 31, tm = threadIdx.x >> 5;
    int m = blockIdx.x * 8 + tm;
    int nc = blockIdx.y * 128 + tn * 4;
    const float* ar = A + m * K;
    float ax = 0, ay = 0, az = 0, aw = 0;
#pragma unroll 16
    for (int kk = 0; kk < K; kk++) {
        float a = ar[kk];
        float4 b = *(const float4*)(B + kk * NT + nc);
        ax += a * b.x; ay += a * b.y; az += a * b.z; aw += a * b.w;
    }
    float4 bb = *(const float4*)(bias + nc);
    ax += bb.x; ay += bb.y; az += bb.z; aw += bb.w;
    if (RES) {
        float4 rr = *(const float4*)(res + m * NT + nc);
        ax += rr.x; ay += rr.y; az += rr.z; aw += rr.w;
    }
    if (RELU) { ax = fmaxf(ax, 0.f); ay = fmaxf(ay, 0.f); az = fmaxf(az, 0.f); aw = fmaxf(aw, 0.f); }
    *(float4*)(C + m * NT + nc) = make_float4(ax, ay, az, aw);
}

// ---------------- attention ----------------
// Vsum[h][d] = sum_n v[h][n][d]
__global__ __launch_bounds__(256) void vsum_k(const float* __restrict__ v, float* __restrict__ vs) {
    int hd = blockIdx.x;               // 0..127
    int hh = hd >> 4, d = hd & 15;
    __shared__ float sb[256];
    float s = 0;
    for (int n = threadIdx.x; n < NN; n += 256) s += v[hh * (NN * HDIM) + n * HDIM + d];
    sb[threadIdx.x] = s; __syncthreads();
    for (int off = 128; off; off >>= 1) { if (threadIdx.x < off) sb[threadIdx.x] += sb[threadIdx.x + off]; __syncthreads(); }
    if (threadIdx.x == 0) vs[hd] = sb[0];
}

// one wave per (head, node-row); sparse masked softmax with analytic zero-class
__global__ __launch_bounds__(256) void attn_k(const float* __restrict__ q, const float* __restrict__ kb,
                                              const float* __restrict__ vb, const u32* __restrict__ rowptr,
                                              const u32* __restrict__ colidx, const u32* __restrict__ cntv,
                                              const float* __restrict__ vsum, float* __restrict__ ob) {
    int lane = threadIdx.x & 63;
    int widx = blockIdx.x * 4 + (threadIdx.x >> 6);
    int hh = widx >> 11;
    int nn = widx & (NN - 1);
    const float* qr = q + hh * (NN * HDIM) + nn * HDIM;
    float qv[16];
    *(float4*)&qv[0]  = *(const float4*)(qr + 0);
    *(float4*)&qv[4]  = *(const float4*)(qr + 4);
    *(float4*)&qv[8]  = *(const float4*)(qr + 8);
    *(float4*)&qv[12] = *(const float4*)(qr + 12);
    int rs = (int)rowptr[nn], re = (int)rowptr[nn + 1];
    float M = -1e30f, sumw = 0.f;
    float wv[16], sv[16];
#pragma unroll
    for (int i = 0; i < 16; i++) { wv[i] = 0.f; sv[i] = 0.f; }
    for (int base = rs; base < re; base += 64) {
        int e = base + lane;
        bool valid = e < re;
        float s = -1e30f;
        int mcol = 0;
        if (valid) {
            mcol = (int)colidx[e];
            float c = (float)cntv[e];
            const float* kr = kb + hh * (NN * HDIM) + mcol * HDIM;
            float kv[16];
            *(float4*)&kv[0]  = *(const float4*)(kr + 0);
            *(float4*)&kv[4]  = *(const float4*)(kr + 4);
            *(float4*)&kv[8]  = *(const float4*)(kr + 8);
            *(float4*)&kv[12] = *(const float4*)(kr + 12);
            float d = 0.f;
#pragma unroll
            for (int i = 0; i < 16; i++) d += qv[i] * kv[i];
            s = c * d;
        }
        float cm = s;
#pragma unroll
        for (int off = 32; off > 0; off >>= 1) cm = fmaxf(cm, __shfl_xor(cm, off));
        float newM = fmaxf(M, cm);
        float resc = __expf(M - newM);   // 0 on first chunk (M=-1e30)
        sumw *= resc;
#pragma unroll
        for (int i = 0; i < 16; i++) wv[i] *= resc;
        float w = valid ? __expf(s - newM) : 0.f;
        sumw += w;
        if (valid) {
            const float* vr = vb + hh * (NN * HDIM) + mcol * HDIM;
            float vvv[16];
            *(float4*)&vvv[0]  = *(const float4*)(vr + 0);
            *(float4*)&vvv[4]  = *(const float4*)(vr + 4);
            *(float4*)&vvv[8]  = *(const float4*)(vr + 8);
            *(float4*)&vvv[12] = *(const float4*)(vr + 12);
#pragma unroll
            for (int i = 0; i < 16; i++) { wv[i] += w * vvv[i]; sv[i] += vvv[i]; }
        }
        M = newM;
    }
#pragma unroll
    for (int off = 32; off > 0; off >>= 1) {
        sumw += __shfl_xor(sumw, off);
#pragma unroll
        for (int i = 0; i < 16; i++) { wv[i] += __shfl_xor(wv[i], off); sv[i] += __shfl_xor(sv[i], off); }
    }
    if (lane == 0) {
        float rowmax = fmaxf(M, 0.f);
        float f = __expf(M - rowmax);       // 0 if no edges
        float em = __expf(-rowmax);
        float Z = f * sumw + (float)(NN - (re - rs)) * em;
        float inv = 1.f / Z;
        const float* vs = vsum + hh * HDIM;
        float* orow = ob + hh * (NN * HDIM) + nn * HDIM;
        float o0[16];
#pragma unroll
        for (int i = 0; i < 16; i++) o0[i] = (f * wv[i] + em * (vs[i] - sv[i])) * inv;
        *(float4*)(orow + 0)  = make_float4(o0[0], o0[1], o0[2], o0[3]);
        *(float4*)(orow + 4)  = make_float4(o0[4], o0[5], o0[6], o0[7]);
        *(float4*)(orow + 8)  = make_float4(o0[8], o0[9], o0[10], o0[11]);
        *(float4*)(orow + 12) = make_float4(o0[12], o0[13], o0[14], o0[15]);
    }
}

// ---------------- batchnorm ----------------
__global__ __launch_bounds__(256) void bnstat_k(const float* __restrict__ x, float* __restrict__ mean,
                                                float* __restrict__ rstd) {
    int c = blockIdx.x, t = threadIdx.x;
    __shared__ float sb[256];
    __shared__ float msh;
    float s = 0;
    for (int r = t; r < NN; r += 256) s += x[r * DD + c];
    sb[t] = s; __syncthreads();
    for (int off = 128; off; off >>= 1) { if (t < off) sb[t] += sb[t + off]; __syncthreads(); }
    if (t == 0) msh = sb[0] * (1.0f / NN);
    __syncthreads();
    float m = msh;
    float s2 = 0;
    for (int r = t; r < NN; r += 256) { float d = x[r * DD + c] - m; s2 += d * d; }
    sb[t] = s2; __syncthreads();
    for (int off = 128; off; off >>= 1) { if (t < off) sb[t] += sb[t + off]; __syncthreads(); }
    if (t == 0) { mean[c] = m; rstd[c] = rsqrtf(sb[0] * (1.0f / NN) + BNEPS); }
}

__global__ __launch_bounds__(256) void bnnorm_k(const float* __restrict__ x, const float* __restrict__ g,
                                                const float* __restrict__ be, const float* __restrict__ mean,
                                                const float* __restrict__ rstd, float* __restrict__ out) {
    int idx = blockIdx.x * 256 + threadIdx.x;
    int c = idx & 127;
    out[idx] = g[c] * (x[idx] - mean[c]) * rstd[c] + be[c];
}

// ---------------- pooling + head ----------------
__global__ __launch_bounds__(128) void pool_k(const float* __restrict__ h, const int* __restrict__ gid,
                                              float* __restrict__ pooled) {
    int g = blockIdx.x;
    int d = threadIdx.x;
    // binary search contiguous range (gid sorted)
    int lo = 0, hi = NN;
    while (lo < hi) { int mid = (lo + hi) >> 1; if (gid[mid] < g) lo = mid + 1; else hi = mid; }
    int start = lo;
    lo = start; hi = NN;
    while (lo < hi) { int mid = (lo + hi) >> 1; if (gid[mid] <= g) lo = mid + 1; else hi = mid; }
    int end = lo;
    float s = 0;
    for (int r = start; r < end; r++) s += h[r * DD + d];
    pooled[g * DD + d] = s;
}

__global__ __launch_bounds__(256) void head_k(const float* __restrict__ pooled, const float* __restrict__ W1,
                                              const float* __restrict__ b1, const float* __restrict__ W2,
                                              const float* __restrict__ b2, float* __restrict__ out) {
    int g = blockIdx.x;
    __shared__ float p[128], midv[128];
    if (threadIdx.x < 128) p[threadIdx.x] = pooled[g * DD + threadIdx.x];
    __syncthreads();
    if (threadIdx.x < 128) {
        int d = threadIdx.x;
        float acc = b1[d];
        for (int k2 = 0; k2 < 128; k2++) acc += p[k2] * W1[k2 * 128 + d];
        midv[d] = fmaxf(acc, 0.f);
    }
    __syncthreads();
    if (threadIdx.x < 64) {
        int j = threadIdx.x;
        float acc = b2[j];
        for (int k2 = 0; k2 < 128; k2++) acc += midv[k2] * W2[k2 * 64 + j];
        out[g * 64 + j] = acc;
    }
}

// ---------------- host ----------------
extern "C" void kernel_launch(void* const* d_in, const int* in_sizes, int n_in,
                              void* d_out, int out_size, void* d_ws, size_t ws_size,
                              hipStream_t stream) {
    (void)n_in; (void)out_size; (void)ws_size;
    const float* X      = (const float*)d_in[0];
    const float* pos    = (const float*)d_in[1];
    const int*   ei     = (const int*)d_in[2];
    const int*   gid    = (const int*)d_in[3];
    const float* proj_W = (const float*)d_in[5];
    const float* proj_b = (const float*)d_in[6];
    const float* pe_W   = (const float*)d_in[7];
    const float* pe_b   = (const float*)d_in[8];
    const float* Wq     = (const float*)d_in[9];
    const float* bq     = (const float*)d_in[10];
    const float* Wk     = (const float*)d_in[11];
    const float* bk     = (const float*)d_in[12];
    const float* Wv     = (const float*)d_in[13];
    const float* bv     = (const float*)d_in[14];
    const float* Wo     = (const float*)d_in[15];
    const float* bo     = (const float*)d_in[16];
    const float* g1     = (const float*)d_in[17];
    const float* beta1  = (const float*)d_in[18];
    const float* W1     = (const float*)d_in[19];
    const float* b1     = (const float*)d_in[20];
    const float* W2     = (const float*)d_in[21];
    const float* b2     = (const float*)d_in[22];
    const float* g2     = (const float*)d_in[23];
    const float* beta2  = (const float*)d_in[24];
    const float* mW1    = (const float*)d_in[25];
    const float* mb1    = (const float*)d_in[26];
    const float* mW2    = (const float*)d_in[27];
    const float* mb2    = (const float*)d_in[28];
    float* out = (float*)d_out;

    int E = in_sizes[2] / 2;

    char* w = (char*)d_ws;
    u32*   Adense = (u32*)(w + 0);                    // 16 MB
    u32*   deg    = (u32*)(w + 16777216);
    u32*   rowptr = (u32*)(w + 16785408);
    u32*   colidx = (u32*)(w + 16793856);
    u32*   cntv   = (u32*)(w + 17056000);
    float* h      = (float*)(w + 17318144);
    float* t1     = (float*)(w + 18366720);
    float* qb     = (float*)(w + 19415296);
    float* kb     = (float*)(w + 20463872);
    float* vb     = (float*)(w + 21512448);
    float* ob     = (float*)(w + 22561024);
    float* mid    = (float*)(w + 23609600);           // 2 MB
    float* vsum   = (float*)(w + 25706752);
    float* meanb  = (float*)(w + 25707264);
    float* rstdb  = (float*)(w + 25707776);
    float* pooled = (float*)(w + 25708288);

    // adjacency -> dedup'd CSR with counts
    hipMemsetAsync(Adense, 0, (size_t)NN * NN * 4, stream);
    scatter_k<<<(E + 255) / 256, 256, 0, stream>>>(ei, Adense, E);
    count_k<<<NN, 256, 0, stream>>>(Adense, deg);
    scan_k<<<1, 256, 0, stream>>>(deg, rowptr);
    emit_k<<<NN, 256, 0, stream>>>(Adense, rowptr, colidx, cntv);

    // input projection
    h0_k<<<NN * DD / 256, 256, 0, stream>>>(X, pos, proj_W, proj_b, pe_W, pe_b, h);

    for (int l = 0; l < LL; l++) {
        const float* Wql = Wq + l * DD * DD;  const float* bql = bq + l * DD;
        const float* Wkl = Wk + l * DD * DD;  const float* bkl = bk + l * DD;
        const float* Wvl = Wv + l * DD * DD;  const float* bvl = bv + l * DD;
        const float* Wol = Wo + l * DD * DD;  const float* bol = bo + l * DD;
        const float* W1l = W1 + l * DD * 2 * DD; const float* b1l = b1 + l * 2 * DD;
        const float* W2l = W2 + l * 2 * DD * DD; const float* b2l = b2 + l * DD;

        qkv_k<<<dim3(NN / 8, 1, 3), 256, 0, stream>>>(h, Wql, bql, Wkl, bkl, Wvl, bvl, qb, kb, vb);
        vsum_k<<<HH * HDIM, 256, 0, stream>>>(vb, vsum);
        attn_k<<<HH * NN / 4, 256, 0, stream>>>(qb, kb, vb, rowptr, colidx, cntv, vsum, ob);
        // t1 = o @ Wo + bo + h   (h is the layer input = residual)
        gemm_k<128, 128, false, true><<<dim3(NN / 8, 1), 256, 0, stream>>>(ob, Wol, bol, h, t1);
        bnstat_k<<<DD, 256, 0, stream>>>(t1, meanb, rstdb);
        bnnorm_k<<<NN * DD / 256, 256, 0, stream>>>(t1, g1 + l * DD, beta1 + l * DD, meanb, rstdb, h);
        // mid = relu(h @ W1 + b1)
        gemm_k<128, 256, true, false><<<dim3(NN / 8, 2), 256, 0, stream>>>(h, W1l, b1l, nullptr, mid);
        // t1 = mid @ W2 + b2 + h
        gemm_k<256, 128, false, true><<<dim3(NN / 8, 1), 256, 0, stream>>>(mid, W2l, b2l, h, t1);
        bnstat_k<<<DD, 256, 0, stream>>>(t1, meanb, rstdb);
        bnnorm_k<<<NN * DD / 256, 256, 0, stream>>>(t1, g2 + l * DD, beta2 + l * DD, meanb, rstdb, h);
    }

    pool_k<<<GG, 128, 0, stream>>>(h, gid, pooled);
    head_k<<<GG, 256, 0, stream>>>(pooled, mW1, mb1, mW2, mb2, out);
}

// Round 2
// 714.452 us; speedup vs baseline: 1.3432x; 1.3432x over previous
//
#include <hip/hip_runtime.h>
#include <hip/hip_bf16.h>

#define NN 2048
#define DD 128
#define HH 8
#define HDIM 16
#define LL 8
#define GG 16
#define BNEPS 1e-5f

typedef unsigned int u32;
typedef unsigned long long u64;

// ---------------- adjacency build ----------------
__global__ __launch_bounds__(256) void scatter_k(const int* __restrict__ ei, u32* __restrict__ A, int E) {
    int e = blockIdx.x * 256 + threadIdx.x;
    if (e < E) {
        int s = ei[e];
        int d = ei[E + e];
        atomicAdd(&A[s * NN + d], 1u);
    }
}

__global__ __launch_bounds__(256) void count_k(const u32* __restrict__ A, u32* __restrict__ deg) {
    int r = blockIdx.x, t = threadIdx.x;
    __shared__ u32 sb[256];
    u32 c = 0;
    for (int j = t; j < NN; j += 256) c += (A[r * NN + j] != 0u) ? 1u : 0u;
    sb[t] = c; __syncthreads();
    for (int off = 128; off; off >>= 1) { if (t < off) sb[t] += sb[t + off]; __syncthreads(); }
    if (t == 0) deg[r] = sb[0];
}

__global__ __launch_bounds__(256) void scan_k(const u32* __restrict__ deg, u32* __restrict__ rowptr) {
    __shared__ u32 part[256];
    int t = threadIdx.x;
    u32 loc[8]; u32 s = 0;
#pragma unroll
    for (int i = 0; i < 8; i++) { loc[i] = deg[t * 8 + i]; s += loc[i]; }
    part[t] = s; __syncthreads();
    for (int off = 1; off < 256; off <<= 1) {
        u32 vprev = (t >= off) ? part[t - off] : 0u;
        __syncthreads();
        part[t] += vprev;
        __syncthreads();
    }
    u32 run = (t == 0) ? 0u : part[t - 1];
    if (t == 0) rowptr[0] = 0u;
#pragma unroll
    for (int i = 0; i < 8; i++) { run += loc[i]; rowptr[t * 8 + i + 1] = run; }
}

__global__ __launch_bounds__(256) void emit_k(const u32* __restrict__ A, const u32* __restrict__ rowptr,
                                              u32* __restrict__ colidx, u32* __restrict__ cntv) {
    int r = blockIdx.x, tid = threadIdx.x;
    int lane = tid & 63, wid = tid >> 6;
    __shared__ u32 wsum[4];
    u32 base = rowptr[r];
    u32 cb = 0;
    for (int c0 = 0; c0 < NN; c0 += 256) {
        int c = c0 + tid;
        u32 a = A[r * NN + c];
        bool p = (a != 0u);
        u64 bal = __ballot(p);
        u32 rankw = (u32)__popcll(bal & ((1ull << lane) - 1ull));
        if (lane == 0) wsum[wid] = (u32)__popcll(bal);
        __syncthreads();
        u32 woff = 0;
#pragma unroll
        for (int w2 = 0; w2 < 4; w2++) if (w2 < wid) woff += wsum[w2];
        u32 tot = wsum[0] + wsum[1] + wsum[2] + wsum[3];
        if (p) { u32 pos = base + cb + woff + rankw; colidx[pos] = (u32)c; cntv[pos] = a; }
        cb += tot;
        __syncthreads();
    }
}

// ---------------- input projection ----------------
__global__ __launch_bounds__(256) void h0_k(const float* __restrict__ X, const float* __restrict__ pe,
                                            const float* __restrict__ pW, const float* __restrict__ pb,
                                            const float* __restrict__ peW, const float* __restrict__ peb,
                                            float* __restrict__ h) {
    int idx = blockIdx.x * 256 + threadIdx.x;
    int r = idx >> 7, d = idx & 127;
    float acc = pb[d] + peb[d];
    acc += X[r * 4 + 0] * pW[0 * DD + d];
    acc += X[r * 4 + 1] * pW[1 * DD + d];
    acc += X[r * 4 + 2] * pW[2 * DD + d];
    acc += X[r * 4 + 3] * pW[3 * DD + d];
    acc += pe[r * 2 + 0] * peW[0 * DD + d];
    acc += pe[r * 2 + 1] * peW[1 * DD + d];
    h[idx] = acc;
}

// ---------------- GEMMs ----------------
// 16 rows x 128 cols per block; thread: 2 rows (m0, m0+8) x 4 cols; k unrolled x4
template <int K, int NT, bool RELU, bool RES>
__global__ __launch_bounds__(256) void gemm2_k(const float* __restrict__ A, const float* __restrict__ B,
                                               const float* __restrict__ bias, const float* __restrict__ res,
                                               float* __restrict__ C) {
    int tn = threadIdx.x & 31, tr = threadIdx.x >> 5;
    int m0 = blockIdx.x * 16 + tr;
    int m1 = m0 + 8;
    int nc = blockIdx.y * 128 + tn * 4;
    const float* a0 = A + m0 * K;
    const float* a1 = A + m1 * K;
    float acc0[4] = {0.f, 0.f, 0.f, 0.f};
    float acc1[4] = {0.f, 0.f, 0.f, 0.f};
#pragma unroll
    for (int k = 0; k < K; k += 4) {
        float4 av0 = *(const float4*)(a0 + k);
        float4 av1 = *(const float4*)(a1 + k);
        float am0[4] = {av0.x, av0.y, av0.z, av0.w};
        float am1[4] = {av1.x, av1.y, av1.z, av1.w};
#pragma unroll
        for (int kk = 0; kk < 4; kk++) {
            float4 bv = *(const float4*)(B + (k + kk) * NT + nc);
            acc0[0] += am0[kk] * bv.x; acc0[1] += am0[kk] * bv.y;
            acc0[2] += am0[kk] * bv.z; acc0[3] += am0[kk] * bv.w;
            acc1[0] += am1[kk] * bv.x; acc1[1] += am1[kk] * bv.y;
            acc1[2] += am1[kk] * bv.z; acc1[3] += am1[kk] * bv.w;
        }
    }
    float4 bb = *(const float4*)(bias + nc);
    acc0[0] += bb.x; acc0[1] += bb.y; acc0[2] += bb.z; acc0[3] += bb.w;
    acc1[0] += bb.x; acc1[1] += bb.y; acc1[2] += bb.z; acc1[3] += bb.w;
    if (RES) {
        float4 r0 = *(const float4*)(res + m0 * NT + nc);
        float4 r1 = *(const float4*)(res + m1 * NT + nc);
        acc0[0] += r0.x; acc0[1] += r0.y; acc0[2] += r0.z; acc0[3] += r0.w;
        acc1[0] += r1.x; acc1[1] += r1.y; acc1[2] += r1.z; acc1[3] += r1.w;
    }
    if (RELU) {
#pragma unroll
        for (int i = 0; i < 4; i++) { acc0[i] = fmaxf(acc0[i], 0.f); acc1[i] = fmaxf(acc1[i], 0.f); }
    }
    *(float4*)(C + m0 * NT + nc) = make_float4(acc0[0], acc0[1], acc0[2], acc0[3]);
    *(float4*)(C + m1 * NT + nc) = make_float4(acc1[0], acc1[1], acc1[2], acc1[3]);
}

// qkv: z picks {q,k,v}; q scaled by 0.25
__global__ __launch_bounds__(256) void qkv2_k(const float* __restrict__ h,
                                              const float* __restrict__ Wq, const float* __restrict__ bq,
                                              const float* __restrict__ Wk, const float* __restrict__ bk,
                                              const float* __restrict__ Wv, const float* __restrict__ bv,
                                              float* __restrict__ q, float* __restrict__ k, float* __restrict__ v) {
    int z = blockIdx.z;
    const float* W = (z == 0) ? Wq : ((z == 1) ? Wk : Wv);
    const float* bias = (z == 0) ? bq : ((z == 1) ? bk : bv);
    float* out = (z == 0) ? q : ((z == 1) ? k : v);
    float scale = (z == 0) ? 0.25f : 1.0f;
    int tn = threadIdx.x & 31, tr = threadIdx.x >> 5;
    int m0 = blockIdx.x * 16 + tr;
    int m1 = m0 + 8;
    int nc = tn * 4;
    const float* a0 = h + m0 * DD;
    const float* a1 = h + m1 * DD;
    float acc0[4] = {0.f, 0.f, 0.f, 0.f};
    float acc1[4] = {0.f, 0.f, 0.f, 0.f};
#pragma unroll
    for (int kk0 = 0; kk0 < DD; kk0 += 4) {
        float4 av0 = *(const float4*)(a0 + kk0);
        float4 av1 = *(const float4*)(a1 + kk0);
        float am0[4] = {av0.x, av0.y, av0.z, av0.w};
        float am1[4] = {av1.x, av1.y, av1.z, av1.w};
#pragma unroll
        for (int kk = 0; kk < 4; kk++) {
            float4 bv = *(const float4*)(W + (kk0 + kk) * DD + nc);
            acc0[0] += am0[kk] * bv.x; acc0[1] += am0[kk] * bv.y;
            acc0[2] += am0[kk] * bv.z; acc0[3] += am0[kk] * bv.w;
            acc1[0] += am1[kk] * bv.x; acc1[1] += am1[kk] * bv.y;
            acc1[2] += am1[kk] * bv.z; acc1[3] += am1[kk] * bv.w;
        }
    }
    float4 bb = *(const float4*)(bias + nc);
    float o0[4], o1[4];
    o0[0] = (acc0[0] + bb.x) * scale; o0[1] = (acc0[1] + bb.y) * scale;
    o0[2] = (acc0[2] + bb.z) * scale; o0[3] = (acc0[3] + bb.w) * scale;
    o1[0] = (acc1[0] + bb.x) * scale; o1[1] = (acc1[1] + bb.y) * scale;
    o1[2] = (acc1[2] + bb.z) * scale; o1[3] = (acc1[3] + bb.w) * scale;
    *(float4*)(out + m0 * DD + nc) = make_float4(o0[0], o0[1], o0[2], o0[3]);
    *(float4*)(out + m1 * DD + nc) = make_float4(o1[0], o1[1], o1[2], o1[3]);
}

// ---------------- attention ----------------
__global__ __launch_bounds__(256) void vsum_k(const float* __restrict__ v, float* __restrict__ vs) {
    int hd = blockIdx.x;               // 0..127
    int hh = hd >> 4, d = hd & 15;
    __shared__ float sb[256];
    float s = 0;
    for (int n = threadIdx.x; n < NN; n += 256) s += v[hh * (NN * HDIM) + n * HDIM + d];
    sb[threadIdx.x] = s; __syncthreads();
    for (int off = 128; off; off >>= 1) { if (threadIdx.x < off) sb[threadIdx.x] += sb[threadIdx.x + off]; __syncthreads(); }
    if (threadIdx.x == 0) vs[hd] = sb[0];
}

// attn v2: 16-lane group per (head,row); two-pass with cached scores; zero-class folded
// o = (sum_e (w_e - em) v_e + em*vsum) / (sum_e w_e + (N-deg)*em),  w_e = exp(s_e - rowmax)
__global__ __launch_bounds__(256) void attn2_k(const float* __restrict__ q, const float* __restrict__ kb,
                                               const float* __restrict__ vb, const u32* __restrict__ rowptr,
                                               const u32* __restrict__ colidx, const u32* __restrict__ cntv,
                                               const float* __restrict__ vsum, float* __restrict__ ob) {
    int tid = threadIdx.x;
    int lane = tid & 15;
    int gidx = blockIdx.x * 16 + (tid >> 4);
    int hh = gidx >> 11;
    int nn = gidx & (NN - 1);
    const float* qr = q + hh * (NN * HDIM) + nn * HDIM;
    float qv[16];
    *(float4*)&qv[0]  = *(const float4*)(qr + 0);
    *(float4*)&qv[4]  = *(const float4*)(qr + 4);
    *(float4*)&qv[8]  = *(const float4*)(qr + 8);
    *(float4*)&qv[12] = *(const float4*)(qr + 12);
    int rs = (int)rowptr[nn], re = (int)rowptr[nn + 1];
    int deg = re - rs;

    float s[8];
    int mc[8];
    float lm = -1e30f;
    // pass 1: scores (first 8 chunks cached in registers)
#pragma unroll
    for (int ch = 0; ch < 8; ch++) {
        s[ch] = -1e30f; mc[ch] = 0;
        if (ch * 16 < deg) {
            int e = rs + ch * 16 + lane;
            if (e < re) {
                mc[ch] = (int)colidx[e];
                float c = (float)cntv[e];
                const float* kr = kb + hh * (NN * HDIM) + mc[ch] * HDIM;
                float kv[16];
                *(float4*)&kv[0]  = *(const float4*)(kr + 0);
                *(float4*)&kv[4]  = *(const float4*)(kr + 4);
                *(float4*)&kv[8]  = *(const float4*)(kr + 8);
                *(float4*)&kv[12] = *(const float4*)(kr + 12);
                float d = 0.f;
#pragma unroll
                for (int i = 0; i < 16; i++) d += qv[i] * kv[i];
                s[ch] = c * d;
            }
            lm = fmaxf(lm, s[ch]);
        }
    }
    // rare tail (deg > 128): recompute path
    for (int base = rs + 128; base < re; base += 16) {
        int e = base + lane;
        if (e < re) {
            int m2 = (int)colidx[e];
            float c = (float)cntv[e];
            const float* kr = kb + hh * (NN * HDIM) + m2 * HDIM;
            float d = 0.f;
#pragma unroll
            for (int i = 0; i < 16; i++) d += qv[i] * kr[i];
            lm = fmaxf(lm, c * d);
        }
    }
    // group max reduce (16 lanes)
#pragma unroll
    for (int off = 1; off < 16; off <<= 1) lm = fmaxf(lm, __shfl_xor(lm, off));
    float rowmax = fmaxf(lm, 0.f);
    float em = __expf(-rowmax);

    // pass 2: weighted V accumulation
    float z = 0.f;
    float acc[16];
#pragma unroll
    for (int i = 0; i < 16; i++) acc[i] = 0.f;
#pragma unroll
    for (int ch = 0; ch < 8; ch++) {
        if (ch * 16 < deg) {
            int e = rs + ch * 16 + lane;
            if (e < re) {
                float w = __expf(s[ch] - rowmax);
                z += w;
                float coef = w - em;
                const float* vr = vb + hh * (NN * HDIM) + mc[ch] * HDIM;
                float vv[16];
                *(float4*)&vv[0]  = *(const float4*)(vr + 0);
                *(float4*)&vv[4]  = *(const float4*)(vr + 4);
                *(float4*)&vv[8]  = *(const float4*)(vr + 8);
                *(float4*)&vv[12] = *(const float4*)(vr + 12);
#pragma unroll
                for (int i = 0; i < 16; i++) acc[i] += coef * vv[i];
            }
        }
    }
    for (int base = rs + 128; base < re; base += 16) {
        int e = base + lane;
        if (e < re) {
            int m2 = (int)colidx[e];
            float c = (float)cntv[e];
            const float* kr = kb + hh * (NN * HDIM) + m2 * HDIM;
            float d = 0.f;
#pragma unroll
            for (int i = 0; i < 16; i++) d += qv[i] * kr[i];
            float w = __expf(c * d - rowmax);
            z += w;
            float coef = w - em;
            const float* vr = vb + hh * (NN * HDIM) + m2 * HDIM;
#pragma unroll
            for (int i = 0; i < 16; i++) acc[i] += coef * vr[i];
        }
    }
    // group reduce acc[16] + z
#pragma unroll
    for (int off = 1; off < 16; off <<= 1) {
        z += __shfl_xor(z, off);
#pragma unroll
        for (int i = 0; i < 16; i++) acc[i] += __shfl_xor(acc[i], off);
    }
    if (lane == 0) {
        float Z = z + (float)(NN - deg) * em;
        float inv = 1.f / Z;
        const float* vs = vsum + hh * HDIM;
        float* orow = ob + hh * (NN * HDIM) + nn * HDIM;
        float o0[16];
#pragma unroll
        for (int i = 0; i < 16; i++) o0[i] = (acc[i] + em * vs[i]) * inv;
        *(float4*)(orow + 0)  = make_float4(o0[0], o0[1], o0[2], o0[3]);
        *(float4*)(orow + 4)  = make_float4(o0[4], o0[5], o0[6], o0[7]);
        *(float4*)(orow + 8)  = make_float4(o0[8], o0[9], o0[10], o0[11]);
        *(float4*)(orow + 12) = make_float4(o0[12], o0[13], o0[14], o0[15]);
    }
}

// ---------------- fused batchnorm ----------------
// one block per column; values held in registers across stats+normalize
__global__ __launch_bounds__(256) void bn_fused_k(const float* __restrict__ x, const float* __restrict__ g,
                                                  const float* __restrict__ be, float* __restrict__ out) {
    int c = blockIdx.x, t = threadIdx.x;
    __shared__ float sb[256];
    __shared__ float msh, rsh;
    float vreg[8];
    float s = 0.f;
#pragma unroll
    for (int i = 0; i < 8; i++) { vreg[i] = x[(t + 256 * i) * DD + c]; s += vreg[i]; }
    sb[t] = s; __syncthreads();
    for (int off = 128; off; off >>= 1) { if (t < off) sb[t] += sb[t + off]; __syncthreads(); }
    if (t == 0) msh = sb[0] * (1.0f / NN);
    __syncthreads();
    float m = msh;
    float s2 = 0.f;
#pragma unroll
    for (int i = 0; i < 8; i++) { float d = vreg[i] - m; s2 += d * d; }
    sb[t] = s2; __syncthreads();
    for (int off = 128; off; off >>= 1) { if (t < off) sb[t] += sb[t + off]; __syncthreads(); }
    if (t == 0) rsh = rsqrtf(sb[0] * (1.0f / NN) + BNEPS);
    __syncthreads();
    float gc = g[c] * rsh;
    float bc = be[c] - m * gc;
#pragma unroll
    for (int i = 0; i < 8; i++) out[(t + 256 * i) * DD + c] = vreg[i] * gc + bc;
}

// ---------------- pooling + head ----------------
__global__ __launch_bounds__(128) void pool_k(const float* __restrict__ h, const int* __restrict__ gid,
                                              float* __restrict__ pooled) {
    int g = blockIdx.x;
    int d = threadIdx.x;
    int lo = 0, hi = NN;
    while (lo < hi) { int mid = (lo + hi) >> 1; if (gid[mid] < g) lo = mid + 1; else hi = mid; }
    int start = lo;
    lo = start; hi = NN;
    while (lo < hi) { int mid = (lo + hi) >> 1; if (gid[mid] <= g) lo = mid + 1; else hi = mid; }
    int end = lo;
    float s = 0;
    for (int r = start; r < end; r++) s += h[r * DD + d];
    pooled[g * DD + d] = s;
}

__global__ __launch_bounds__(256) void head_k(const float* __restrict__ pooled, const float* __restrict__ W1,
                                              const float* __restrict__ b1, const float* __restrict__ W2,
                                              const float* __restrict__ b2, float* __restrict__ out) {
    int g = blockIdx.x;
    __shared__ float p[128], midv[128];
    if (threadIdx.x < 128) p[threadIdx.x] = pooled[g * DD + threadIdx.x];
    __syncthreads();
    if (threadIdx.x < 128) {
        int d = threadIdx.x;
        float acc = b1[d];
        for (int k2 = 0; k2 < 128; k2++) acc += p[k2] * W1[k2 * 128 + d];
        midv[d] = fmaxf(acc, 0.f);
    }
    __syncthreads();
    if (threadIdx.x < 64) {
        int j = threadIdx.x;
        float acc = b2[j];
        for (int k2 = 0; k2 < 128; k2++) acc += midv[k2] * W2[k2 * 64 + j];
        out[g * 64 + j] = acc;
    }
}

// ---------------- host ----------------
extern "C" void kernel_launch(void* const* d_in, const int* in_sizes, int n_in,
                              void* d_out, int out_size, void* d_ws, size_t ws_size,
                              hipStream_t stream) {
    (void)n_in; (void)out_size; (void)ws_size;
    const float* X      = (const float*)d_in[0];
    const float* pos    = (const float*)d_in[1];
    const int*   ei     = (const int*)d_in[2];
    const int*   gid    = (const int*)d_in[3];
    const float* proj_W = (const float*)d_in[5];
    const float* proj_b = (const float*)d_in[6];
    const float* pe_W   = (const float*)d_in[7];
    const float* pe_b   = (const float*)d_in[8];
    const float* Wq     = (const float*)d_in[9];
    const float* bq     = (const float*)d_in[10];
    const float* Wk     = (const float*)d_in[11];
    const float* bk     = (const float*)d_in[12];
    const float* Wv     = (const float*)d_in[13];
    const float* bv     = (const float*)d_in[14];
    const float* Wo     = (const float*)d_in[15];
    const float* bo     = (const float*)d_in[16];
    const float* g1     = (const float*)d_in[17];
    const float* beta1  = (const float*)d_in[18];
    const float* W1     = (const float*)d_in[19];
    const float* b1     = (const float*)d_in[20];
    const float* W2     = (const float*)d_in[21];
    const float* b2     = (const float*)d_in[22];
    const float* g2     = (const float*)d_in[23];
    const float* beta2  = (const float*)d_in[24];
    const float* mW1    = (const float*)d_in[25];
    const float* mb1    = (const float*)d_in[26];
    const float* mW2    = (const float*)d_in[27];
    const float* mb2    = (const float*)d_in[28];
    float* out = (float*)d_out;

    int E = in_sizes[2] / 2;

    char* w = (char*)d_ws;
    u32*   Adense = (u32*)(w + 0);                    // 16 MB
    u32*   deg    = (u32*)(w + 16777216);
    u32*   rowptr = (u32*)(w + 16785408);
    u32*   colidx = (u32*)(w + 16793856);
    u32*   cntv   = (u32*)(w + 17056000);
    float* h      = (float*)(w + 17318144);
    float* t1     = (float*)(w + 18366720);
    float* qb     = (float*)(w + 19415296);
    float* kb     = (float*)(w + 20463872);
    float* vb     = (float*)(w + 21512448);
    float* ob     = (float*)(w + 22561024);
    float* mid    = (float*)(w + 23609600);           // 2 MB
    float* vsum   = (float*)(w + 25706752);
    float* pooled = (float*)(w + 25708288);

    // adjacency -> dedup'd CSR with counts
    hipMemsetAsync(Adense, 0, (size_t)NN * NN * 4, stream);
    scatter_k<<<(E + 255) / 256, 256, 0, stream>>>(ei, Adense, E);
    count_k<<<NN, 256, 0, stream>>>(Adense, deg);
    scan_k<<<1, 256, 0, stream>>>(deg, rowptr);
    emit_k<<<NN, 256, 0, stream>>>(Adense, rowptr, colidx, cntv);

    // input projection
    h0_k<<<NN * DD / 256, 256, 0, stream>>>(X, pos, proj_W, proj_b, pe_W, pe_b, h);

    for (int l = 0; l < LL; l++) {
        const float* Wql = Wq + l * DD * DD;  const float* bql = bq + l * DD;
        const float* Wkl = Wk + l * DD * DD;  const float* bkl = bk + l * DD;
        const float* Wvl = Wv + l * DD * DD;  const float* bvl = bv + l * DD;
        const float* Wol = Wo + l * DD * DD;  const float* bol = bo + l * DD;
        const float* W1l = W1 + l * DD * 2 * DD; const float* b1l = b1 + l * 2 * DD;
        const float* W2l = W2 + l * 2 * DD * DD; const float* b2l = b2 + l * DD;

        qkv2_k<<<dim3(NN / 16, 1, 3), 256, 0, stream>>>(h, Wql, bql, Wkl, bkl, Wvl, bvl, qb, kb, vb);
        vsum_k<<<HH * HDIM, 256, 0, stream>>>(vb, vsum);
        attn2_k<<<HH * NN / 16, 256, 0, stream>>>(qb, kb, vb, rowptr, colidx, cntv, vsum, ob);
        // t1 = o @ Wo + bo + h
        gemm2_k<128, 128, false, true><<<dim3(NN / 16, 1), 256, 0, stream>>>(ob, Wol, bol, h, t1);
        bn_fused_k<<<DD, 256, 0, stream>>>(t1, g1 + l * DD, beta1 + l * DD, h);
        // mid = relu(h @ W1 + b1)
        gemm2_k<128, 256, true, false><<<dim3(NN / 16, 2), 256, 0, stream>>>(h, W1l, b1l, nullptr, mid);
        // t1 = mid @ W2 + b2 + h
        gemm2_k<256, 128, false, true><<<dim3(NN / 16, 1), 256, 0, stream>>>(mid, W2l, b2l, h, t1);
        bn_fused_k<<<DD, 256, 0, stream>>>(t1, g2 + l * DD, beta2 + l * DD, h);
    }

    pool_k<<<GG, 128, 0, stream>>>(h, gid, pooled);
    head_k<<<GG, 256, 0, stream>>>(pooled, mW1, mb1, mW2, mb2, out);
}

// Round 3
// 500.141 us; speedup vs baseline: 1.9188x; 1.4285x over previous
//
#include <hip/hip_runtime.h>
#include <hip/hip_bf16.h>

#define NN 2048
#define DD 128
#define HH 8
#define HDIM 16
#define LL 8
#define GG 16
#define BNEPS 1e-5f

typedef unsigned int u32;
typedef unsigned long long u64;
typedef __attribute__((ext_vector_type(8))) short bf16x8;
typedef __attribute__((ext_vector_type(8))) unsigned short us8;
typedef __attribute__((ext_vector_type(4))) float f32x4;

__device__ __forceinline__ unsigned short f2bf(float f) {
    union { float f; u32 u; } v; v.f = f;
    u32 u = v.u;
    u32 r = (u + 0x7fffu + ((u >> 16) & 1u)) >> 16;
    return (unsigned short)r;
}

// ---------------- adjacency build ----------------
__global__ __launch_bounds__(256) void scatter_k(const int* __restrict__ ei, u32* __restrict__ A, int E) {
    int e = blockIdx.x * 256 + threadIdx.x;
    if (e < E) {
        int s = ei[e];
        int d = ei[E + e];
        atomicAdd(&A[s * NN + d], 1u);
    }
}

__global__ __launch_bounds__(256) void count_k(const u32* __restrict__ A, u32* __restrict__ deg) {
    int r = blockIdx.x, t = threadIdx.x;
    __shared__ u32 sb[256];
    u32 c = 0;
    for (int j = t; j < NN; j += 256) c += (A[r * NN + j] != 0u) ? 1u : 0u;
    sb[t] = c; __syncthreads();
    for (int off = 128; off; off >>= 1) { if (t < off) sb[t] += sb[t + off]; __syncthreads(); }
    if (t == 0) deg[r] = sb[0];
}

__global__ __launch_bounds__(256) void scan_k(const u32* __restrict__ deg, u32* __restrict__ rowptr) {
    __shared__ u32 part[256];
    int t = threadIdx.x;
    u32 loc[8]; u32 s = 0;
#pragma unroll
    for (int i = 0; i < 8; i++) { loc[i] = deg[t * 8 + i]; s += loc[i]; }
    part[t] = s; __syncthreads();
    for (int off = 1; off < 256; off <<= 1) {
        u32 vprev = (t >= off) ? part[t - off] : 0u;
        __syncthreads();
        part[t] += vprev;
        __syncthreads();
    }
    u32 run = (t == 0) ? 0u : part[t - 1];
    if (t == 0) rowptr[0] = 0u;
#pragma unroll
    for (int i = 0; i < 8; i++) { run += loc[i]; rowptr[t * 8 + i + 1] = run; }
}

__global__ __launch_bounds__(256) void emit_k(const u32* __restrict__ A, const u32* __restrict__ rowptr,
                                              u32* __restrict__ colidx, u32* __restrict__ cntv) {
    int r = blockIdx.x, tid = threadIdx.x;
    int lane = tid & 63, wid = tid >> 6;
    __shared__ u32 wsum[4];
    u32 base = rowptr[r];
    u32 cb = 0;
    for (int c0 = 0; c0 < NN; c0 += 256) {
        int c = c0 + tid;
        u32 a = A[r * NN + c];
        bool p = (a != 0u);
        u64 bal = __ballot(p);
        u32 rankw = (u32)__popcll(bal & ((1ull << lane) - 1ull));
        if (lane == 0) wsum[wid] = (u32)__popcll(bal);
        __syncthreads();
        u32 woff = 0;
#pragma unroll
        for (int w2 = 0; w2 < 4; w2++) if (w2 < wid) woff += wsum[w2];
        u32 tot = wsum[0] + wsum[1] + wsum[2] + wsum[3];
        if (p) { u32 pos = base + cb + woff + rankw; colidx[pos] = (u32)c; cntv[pos] = a; }
        cb += tot;
        __syncthreads();
    }
}

// ---------------- weight fragment conversion ----------------
// slot layout per layer (16384 slots of bf16x8): q[0,2048) k[2048,4096) v[4096,6144)
// o[6144,8192) W1[8192,12288) W2[12288,16384)
// fragment: slot s of a matrix region: lane=s&63, t=s>>6, nt=t%NT, kt=t/NT
// elem j -> W[kt*32 + (lane>>4)*8 + j][nt*16 + (lane&15)]
__global__ __launch_bounds__(256) void wconv_k(const float* __restrict__ Wq, const float* __restrict__ Wk,
                                               const float* __restrict__ Wv, const float* __restrict__ Wo,
                                               const float* __restrict__ W1, const float* __restrict__ W2,
                                               us8* __restrict__ Wf) {
    int tid = blockIdx.x * 256 + threadIdx.x;   // 0..131071
    int layer = tid >> 14;
    int r = tid & 16383;
    const float* src;
    int s, NT, ld;
    if (r < 8192) {
        int reg = r >> 11;         // 0..3 : q,k,v,o
        s = r & 2047;
        NT = 8; ld = 128;
        const float* bases[4] = {Wq, Wk, Wv, Wo};
        src = bases[reg] + layer * 16384;
    } else if (r < 12288) {
        s = r - 8192;
        NT = 16; ld = 256;
        src = W1 + layer * 32768;
    } else {
        s = r - 12288;
        NT = 8; ld = 128;
        src = W2 + layer * 32768;
    }
    int lane = s & 63;
    int t = s >> 6;
    int nt = t % NT;
    int kt = t / NT;
    int col = nt * 16 + (lane & 15);
    int k0 = kt * 32 + (lane >> 4) * 8;
    us8 o;
#pragma unroll
    for (int j = 0; j < 8; j++) o[j] = f2bf(src[(k0 + j) * ld + col]);
    Wf[tid] = o;
}

// ---------------- input projection ----------------
__global__ __launch_bounds__(256) void h0_k(const float* __restrict__ X, const float* __restrict__ pe,
                                            const float* __restrict__ pW, const float* __restrict__ pb,
                                            const float* __restrict__ peW, const float* __restrict__ peb,
                                            float* __restrict__ h, unsigned short* __restrict__ hb) {
    int idx = blockIdx.x * 256 + threadIdx.x;
    int r = idx >> 7, d = idx & 127;
    float acc = pb[d] + peb[d];
    acc += X[r * 4 + 0] * pW[0 * DD + d];
    acc += X[r * 4 + 1] * pW[1 * DD + d];
    acc += X[r * 4 + 2] * pW[2 * DD + d];
    acc += X[r * 4 + 3] * pW[3 * DD + d];
    acc += pe[r * 2 + 0] * peW[0 * DD + d];
    acc += pe[r * 2 + 1] * peW[1 * DD + d];
    h[idx] = acc;
    hb[idx] = f2bf(acc);
}

// ---------------- MFMA GEMMs ----------------
// block = 4 waves; wave w: rows blockIdx.x*64 + w*16, cols blockIdx.y*16
template <int KDIM, int NOUT, bool RELU, bool RES, bool OUTB, bool OUTF>
__global__ __launch_bounds__(256) void mfma_gemm_k(const unsigned short* __restrict__ A,
                                                   const bf16x8* __restrict__ Wf,
                                                   const float* __restrict__ bias,
                                                   const float* __restrict__ res,
                                                   float* __restrict__ Cf,
                                                   unsigned short* __restrict__ Cb) {
    constexpr int KT = KDIM / 32;
    constexpr int NTl = NOUT / 16;
    int lane = threadIdx.x & 63;
    int wv = threadIdx.x >> 6;
    int m0 = blockIdx.x * 64 + wv * 16;
    int nt = blockIdx.y;
    int arow = m0 + (lane & 15);
    int kb0 = (lane >> 4) * 8;
    const unsigned short* ap = A + arow * KDIM + kb0;
    f32x4 acc = {0.f, 0.f, 0.f, 0.f};
#pragma unroll
    for (int kt = 0; kt < KT; kt++) {
        bf16x8 af = *(const bf16x8*)(ap + kt * 32);
        bf16x8 bfr = Wf[(kt * NTl + nt) * 64 + lane];
        acc = __builtin_amdgcn_mfma_f32_16x16x32_bf16(af, bfr, acc, 0, 0, 0);
    }
    int col = nt * 16 + (lane & 15);
    int r0 = m0 + (lane >> 4) * 4;
    float bv = bias[col];
#pragma unroll
    for (int j = 0; j < 4; j++) {
        float v = acc[j] + bv;
        if (RES) v += res[(r0 + j) * NOUT + col];
        if (RELU) v = fmaxf(v, 0.f);
        if (OUTF) Cf[(r0 + j) * NOUT + col] = v;
        if (OUTB) Cb[(r0 + j) * NOUT + col] = f2bf(v);
    }
}

// fused q,k,v via blockIdx.z; q scaled by 0.25 after bias
__global__ __launch_bounds__(256) void qkv_mfma_k(const unsigned short* __restrict__ A,
                                                  const bf16x8* __restrict__ Wfq,
                                                  const bf16x8* __restrict__ Wfk,
                                                  const bf16x8* __restrict__ Wfv,
                                                  const float* __restrict__ bq,
                                                  const float* __restrict__ bk,
                                                  const float* __restrict__ bv,
                                                  float* __restrict__ q, float* __restrict__ k,
                                                  float* __restrict__ v) {
    int z = blockIdx.z;
    const bf16x8* Wf = (z == 0) ? Wfq : ((z == 1) ? Wfk : Wfv);
    const float* bias = (z == 0) ? bq : ((z == 1) ? bk : bv);
    float* out = (z == 0) ? q : ((z == 1) ? k : v);
    float scale = (z == 0) ? 0.25f : 1.0f;
    int lane = threadIdx.x & 63;
    int wv = threadIdx.x >> 6;
    int m0 = blockIdx.x * 64 + wv * 16;
    int nt = blockIdx.y;
    int arow = m0 + (lane & 15);
    int kb0 = (lane >> 4) * 8;
    const unsigned short* ap = A + arow * DD + kb0;
    f32x4 acc = {0.f, 0.f, 0.f, 0.f};
#pragma unroll
    for (int kt = 0; kt < 4; kt++) {
        bf16x8 af = *(const bf16x8*)(ap + kt * 32);
        bf16x8 bfr = Wf[(kt * 8 + nt) * 64 + lane];
        acc = __builtin_amdgcn_mfma_f32_16x16x32_bf16(af, bfr, acc, 0, 0, 0);
    }
    int col = nt * 16 + (lane & 15);
    int r0 = m0 + (lane >> 4) * 4;
    float bb = bias[col];
#pragma unroll
    for (int j = 0; j < 4; j++) out[(r0 + j) * DD + col] = (acc[j] + bb) * scale;
}

// ---------------- attention ----------------
__global__ __launch_bounds__(256) void vsum_k(const float* __restrict__ v, float* __restrict__ vs) {
    int hd = blockIdx.x;               // 0..127
    int hh = hd >> 4, d = hd & 15;
    __shared__ float sb[256];
    float s = 0;
    for (int n = threadIdx.x; n < NN; n += 256) s += v[hh * (NN * HDIM) + n * HDIM + d];
    sb[threadIdx.x] = s; __syncthreads();
    for (int off = 128; off; off >>= 1) { if (threadIdx.x < off) sb[threadIdx.x] += sb[threadIdx.x + off]; __syncthreads(); }
    if (threadIdx.x == 0) vs[hd] = sb[0];
}

// attn: 16-lane group per (head,row); two-pass with cached scores; zero-class folded
__global__ __launch_bounds__(256) void attn2_k(const float* __restrict__ q, const float* __restrict__ kb,
                                               const float* __restrict__ vb, const u32* __restrict__ rowptr,
                                               const u32* __restrict__ colidx, const u32* __restrict__ cntv,
                                               const float* __restrict__ vsum, unsigned short* __restrict__ obb) {
    int tid = threadIdx.x;
    int lane = tid & 15;
    int gidx = blockIdx.x * 16 + (tid >> 4);
    int hh = gidx >> 11;
    int nn = gidx & (NN - 1);
    const float* qr = q + hh * (NN * HDIM) + nn * HDIM;
    float qv[16];
    *(float4*)&qv[0]  = *(const float4*)(qr + 0);
    *(float4*)&qv[4]  = *(const float4*)(qr + 4);
    *(float4*)&qv[8]  = *(const float4*)(qr + 8);
    *(float4*)&qv[12] = *(const float4*)(qr + 12);
    int rs = (int)rowptr[nn], re = (int)rowptr[nn + 1];
    int deg = re - rs;

    float s[8];
    int mc[8];
    float lm = -1e30f;
#pragma unroll
    for (int ch = 0; ch < 8; ch++) {
        s[ch] = -1e30f; mc[ch] = 0;
        if (ch * 16 < deg) {
            int e = rs + ch * 16 + lane;
            if (e < re) {
                mc[ch] = (int)colidx[e];
                float c = (float)cntv[e];
                const float* kr = kb + hh * (NN * HDIM) + mc[ch] * HDIM;
                float kv[16];
                *(float4*)&kv[0]  = *(const float4*)(kr + 0);
                *(float4*)&kv[4]  = *(const float4*)(kr + 4);
                *(float4*)&kv[8]  = *(const float4*)(kr + 8);
                *(float4*)&kv[12] = *(const float4*)(kr + 12);
                float d = 0.f;
#pragma unroll
                for (int i = 0; i < 16; i++) d += qv[i] * kv[i];
                s[ch] = c * d;
            }
            lm = fmaxf(lm, s[ch]);
        }
    }
    for (int base = rs + 128; base < re; base += 16) {
        int e = base + lane;
        if (e < re) {
            int m2 = (int)colidx[e];
            float c = (float)cntv[e];
            const float* kr = kb + hh * (NN * HDIM) + m2 * HDIM;
            float d = 0.f;
#pragma unroll
            for (int i = 0; i < 16; i++) d += qv[i] * kr[i];
            lm = fmaxf(lm, c * d);
        }
    }
#pragma unroll
    for (int off = 1; off < 16; off <<= 1) lm = fmaxf(lm, __shfl_xor(lm, off));
    float rowmax = fmaxf(lm, 0.f);
    float em = __expf(-rowmax);

    float z = 0.f;
    float acc[16];
#pragma unroll
    for (int i = 0; i < 16; i++) acc[i] = 0.f;
#pragma unroll
    for (int ch = 0; ch < 8; ch++) {
        if (ch * 16 < deg) {
            int e = rs + ch * 16 + lane;
            if (e < re) {
                float w = __expf(s[ch] - rowmax);
                z += w;
                float coef = w - em;
                const float* vr = vb + hh * (NN * HDIM) + mc[ch] * HDIM;
                float vv[16];
                *(float4*)&vv[0]  = *(const float4*)(vr + 0);
                *(float4*)&vv[4]  = *(const float4*)(vr + 4);
                *(float4*)&vv[8]  = *(const float4*)(vr + 8);
                *(float4*)&vv[12] = *(const float4*)(vr + 12);
#pragma unroll
                for (int i = 0; i < 16; i++) acc[i] += coef * vv[i];
            }
        }
    }
    for (int base = rs + 128; base < re; base += 16) {
        int e = base + lane;
        if (e < re) {
            int m2 = (int)colidx[e];
            float c = (float)cntv[e];
            const float* kr = kb + hh * (NN * HDIM) + m2 * HDIM;
            float d = 0.f;
#pragma unroll
            for (int i = 0; i < 16; i++) d += qv[i] * kr[i];
            float w = __expf(c * d - rowmax);
            z += w;
            float coef = w - em;
            const float* vr = vb + hh * (NN * HDIM) + m2 * HDIM;
#pragma unroll
            for (int i = 0; i < 16; i++) acc[i] += coef * vr[i];
        }
    }
#pragma unroll
    for (int off = 1; off < 16; off <<= 1) {
        z += __shfl_xor(z, off);
#pragma unroll
        for (int i = 0; i < 16; i++) acc[i] += __shfl_xor(acc[i], off);
    }
    if (lane == 0) {
        float Z = z + (float)(NN - deg) * em;
        float inv = 1.f / Z;
        const float* vs = vsum + hh * HDIM;
        unsigned short* orow = obb + hh * (NN * HDIM) + nn * HDIM;
        us8 lo, hi;
#pragma unroll
        for (int i = 0; i < 8; i++) {
            lo[i] = f2bf((acc[i] + em * vs[i]) * inv);
            hi[i] = f2bf((acc[i + 8] + em * vs[i + 8]) * inv);
        }
        *(us8*)(orow + 0) = lo;
        *(us8*)(orow + 8) = hi;
    }
}

// ---------------- fused batchnorm (writes fp32 + bf16) ----------------
__global__ __launch_bounds__(256) void bn_fused_k(const float* __restrict__ x, const float* __restrict__ g,
                                                  const float* __restrict__ be, float* __restrict__ out,
                                                  unsigned short* __restrict__ outb) {
    int c = blockIdx.x, t = threadIdx.x;
    __shared__ float sb[256];
    __shared__ float msh, rsh;
    float vreg[8];
    float s = 0.f;
#pragma unroll
    for (int i = 0; i < 8; i++) { vreg[i] = x[(t + 256 * i) * DD + c]; s += vreg[i]; }
    sb[t] = s; __syncthreads();
    for (int off = 128; off; off >>= 1) { if (t < off) sb[t] += sb[t + off]; __syncthreads(); }
    if (t == 0) msh = sb[0] * (1.0f / NN);
    __syncthreads();
    float m = msh;
    float s2 = 0.f;
#pragma unroll
    for (int i = 0; i < 8; i++) { float d = vreg[i] - m; s2 += d * d; }
    sb[t] = s2; __syncthreads();
    for (int off = 128; off; off >>= 1) { if (t < off) sb[t] += sb[t + off]; __syncthreads(); }
    if (t == 0) rsh = rsqrtf(sb[0] * (1.0f / NN) + BNEPS);
    __syncthreads();
    float gc = g[c] * rsh;
    float bc = be[c] - m * gc;
#pragma unroll
    for (int i = 0; i < 8; i++) {
        float o = vreg[i] * gc + bc;
        out[(t + 256 * i) * DD + c] = o;
        outb[(t + 256 * i) * DD + c] = f2bf(o);
    }
}

// ---------------- pooling + head ----------------
__global__ __launch_bounds__(128) void pool_k(const float* __restrict__ h, const int* __restrict__ gid,
                                              float* __restrict__ pooled) {
    int g = blockIdx.x;
    int d = threadIdx.x;
    int lo = 0, hi = NN;
    while (lo < hi) { int mid = (lo + hi) >> 1; if (gid[mid] < g) lo = mid + 1; else hi = mid; }
    int start = lo;
    lo = start; hi = NN;
    while (lo < hi) { int mid = (lo + hi) >> 1; if (gid[mid] <= g) lo = mid + 1; else hi = mid; }
    int end = lo;
    float s = 0;
    for (int r = start; r < end; r++) s += h[r * DD + d];
    pooled[g * DD + d] = s;
}

__global__ __launch_bounds__(256) void head_k(const float* __restrict__ pooled, const float* __restrict__ W1,
                                              const float* __restrict__ b1, const float* __restrict__ W2,
                                              const float* __restrict__ b2, float* __restrict__ out) {
    int g = blockIdx.x;
    __shared__ float p[128], midv[128];
    if (threadIdx.x < 128) p[threadIdx.x] = pooled[g * DD + threadIdx.x];
    __syncthreads();
    if (threadIdx.x < 128) {
        int d = threadIdx.x;
        float acc = b1[d];
        for (int k2 = 0; k2 < 128; k2++) acc += p[k2] * W1[k2 * 128 + d];
        midv[d] = fmaxf(acc, 0.f);
    }
    __syncthreads();
    if (threadIdx.x < 64) {
        int j = threadIdx.x;
        float acc = b2[j];
        for (int k2 = 0; k2 < 128; k2++) acc += midv[k2] * W2[k2 * 64 + j];
        out[g * 64 + j] = acc;
    }
}

// ---------------- host ----------------
extern "C" void kernel_launch(void* const* d_in, const int* in_sizes, int n_in,
                              void* d_out, int out_size, void* d_ws, size_t ws_size,
                              hipStream_t stream) {
    (void)n_in; (void)out_size; (void)ws_size;
    const float* X      = (const float*)d_in[0];
    const float* pos    = (const float*)d_in[1];
    const int*   ei     = (const int*)d_in[2];
    const int*   gid    = (const int*)d_in[3];
    const float* proj_W = (const float*)d_in[5];
    const float* proj_b = (const float*)d_in[6];
    const float* pe_W   = (const float*)d_in[7];
    const float* pe_b   = (const float*)d_in[8];
    const float* Wq     = (const float*)d_in[9];
    const float* bq     = (const float*)d_in[10];
    const float* Wk     = (const float*)d_in[11];
    const float* bk     = (const float*)d_in[12];
    const float* Wv     = (const float*)d_in[13];
    const float* bv     = (const float*)d_in[14];
    const float* Wo     = (const float*)d_in[15];
    const float* bo     = (const float*)d_in[16];
    const float* g1     = (const float*)d_in[17];
    const float* beta1  = (const float*)d_in[18];
    const float* W1     = (const float*)d_in[19];
    const float* b1     = (const float*)d_in[20];
    const float* W2     = (const float*)d_in[21];
    const float* b2     = (const float*)d_in[22];
    const float* g2     = (const float*)d_in[23];
    const float* beta2  = (const float*)d_in[24];
    const float* mW1    = (const float*)d_in[25];
    const float* mb1    = (const float*)d_in[26];
    const float* mW2    = (const float*)d_in[27];
    const float* mb2    = (const float*)d_in[28];
    float* out = (float*)d_out;

    int E = in_sizes[2] / 2;

    char* w = (char*)d_ws;
    u32*   Adense = (u32*)(w + 0);
    u32*   deg    = (u32*)(w + 16777216);
    u32*   rowptr = (u32*)(w + 16785408);
    u32*   colidx = (u32*)(w + 16793856);
    u32*   cntv   = (u32*)(w + 17056000);
    float* h      = (float*)(w + 17318144);
    unsigned short* hb   = (unsigned short*)(w + 18366720);   // 0.5 MB
    float* t1     = (float*)(w + 18891008);
    float* qb     = (float*)(w + 19939584);
    float* kb     = (float*)(w + 20988160);
    float* vb     = (float*)(w + 22036736);
    unsigned short* obb  = (unsigned short*)(w + 23085312);   // 0.5 MB
    unsigned short* midb = (unsigned short*)(w + 23609600);   // 1 MB
    float* vsum   = (float*)(w + 24658176);
    float* pooled = (float*)(w + 24658688);
    bf16x8* Wf    = (bf16x8*)(w + 24666880);                  // 2 MB

    // adjacency -> dedup'd CSR with counts
    hipMemsetAsync(Adense, 0, (size_t)NN * NN * 4, stream);
    scatter_k<<<(E + 255) / 256, 256, 0, stream>>>(ei, Adense, E);
    count_k<<<NN, 256, 0, stream>>>(Adense, deg);
    scan_k<<<1, 256, 0, stream>>>(deg, rowptr);
    emit_k<<<NN, 256, 0, stream>>>(Adense, rowptr, colidx, cntv);

    // weight fragments (all layers, one launch)
    wconv_k<<<512, 256, 0, stream>>>(Wq, Wk, Wv, Wo, W1, W2, (us8*)Wf);

    // input projection
    h0_k<<<NN * DD / 256, 256, 0, stream>>>(X, pos, proj_W, proj_b, pe_W, pe_b, h, hb);

    for (int l = 0; l < LL; l++) {
        const bf16x8* Wfl = Wf + l * 16384;
        const bf16x8* Wfq = Wfl + 0;
        const bf16x8* Wfk = Wfl + 2048;
        const bf16x8* Wfv = Wfl + 4096;
        const bf16x8* Wfo = Wfl + 6144;
        const bf16x8* Wf1 = Wfl + 8192;
        const bf16x8* Wf2 = Wfl + 12288;
        const float* bql = bq + l * DD;
        const float* bkl = bk + l * DD;
        const float* bvl = bv + l * DD;
        const float* bol = bo + l * DD;
        const float* b1l = b1 + l * 2 * DD;
        const float* b2l = b2 + l * DD;

        qkv_mfma_k<<<dim3(NN / 64, 8, 3), 256, 0, stream>>>(hb, Wfq, Wfk, Wfv, bql, bkl, bvl, qb, kb, vb);
        vsum_k<<<HH * HDIM, 256, 0, stream>>>(vb, vsum);
        attn2_k<<<HH * NN / 16, 256, 0, stream>>>(qb, kb, vb, rowptr, colidx, cntv, vsum, obb);
        // t1 = o @ Wo + bo + h
        mfma_gemm_k<128, 128, false, true, false, true>
            <<<dim3(NN / 64, 8), 256, 0, stream>>>(obb, Wfo, bol, h, t1, nullptr);
        bn_fused_k<<<DD, 256, 0, stream>>>(t1, g1 + l * DD, beta1 + l * DD, h, hb);
        // midb = relu(h @ W1 + b1)  (bf16 out only)
        mfma_gemm_k<128, 256, true, false, true, false>
            <<<dim3(NN / 64, 16), 256, 0, stream>>>(hb, Wf1, b1l, nullptr, nullptr, midb);
        // t1 = mid @ W2 + b2 + h
        mfma_gemm_k<256, 128, false, true, false, true>
            <<<dim3(NN / 64, 8), 256, 0, stream>>>(midb, Wf2, b2l, h, t1, nullptr);
        bn_fused_k<<<DD, 256, 0, stream>>>(t1, g2 + l * DD, beta2 + l * DD, h, hb);
    }

    pool_k<<<GG, 128, 0, stream>>>(h, gid, pooled);
    head_k<<<GG, 256, 0, stream>>>(pooled, mW1, mb1, mW2, mb2, out);
}

// Round 6
// 401.883 us; speedup vs baseline: 2.3879x; 1.2445x over previous
//
#include <hip/hip_runtime.h>
#include <hip/hip_bf16.h>

#define NN 2048
#define DD 128
#define HH 8
#define HDIM 16
#define LL 8
#define GG 16
#define BNEPS 1e-5f

typedef unsigned int u32;
typedef unsigned long long u64;
typedef __attribute__((ext_vector_type(8))) short bf16x8;
typedef __attribute__((ext_vector_type(8))) unsigned short us8;
typedef __attribute__((ext_vector_type(4))) float f32x4;

__device__ __forceinline__ unsigned short f2bf(float f) {
    union { float f; u32 u; } v; v.f = f;
    u32 u = v.u;
    u32 r = (u + 0x7fffu + ((u >> 16) & 1u)) >> 16;
    return (unsigned short)r;
}

// ---------------- workspace zeroing (graph-capture-safe; replaces hipMemsetAsync) ----------------
__global__ __launch_bounds__(256) void zero_k(uint4* __restrict__ p) {
    p[blockIdx.x * 256 + threadIdx.x] = make_uint4(0u, 0u, 0u, 0u);
}

// ---------------- adjacency build ----------------
__global__ __launch_bounds__(256) void scatter_k(const int* __restrict__ ei, u32* __restrict__ A, int E) {
    int e = blockIdx.x * 256 + threadIdx.x;
    if (e < E) {
        int s = ei[e];
        int d = ei[E + e];
        atomicAdd(&A[s * NN + d], 1u);
    }
}

__global__ __launch_bounds__(256) void count_k(const u32* __restrict__ A, u32* __restrict__ deg) {
    int r = blockIdx.x, t = threadIdx.x;
    __shared__ u32 sb[256];
    u32 c = 0;
    for (int j = t; j < NN; j += 256) c += (A[r * NN + j] != 0u) ? 1u : 0u;
    sb[t] = c; __syncthreads();
    for (int off = 128; off; off >>= 1) { if (t < off) sb[t] += sb[t + off]; __syncthreads(); }
    if (t == 0) deg[r] = sb[0];
}

__global__ __launch_bounds__(256) void scan_k(const u32* __restrict__ deg, u32* __restrict__ rowptr) {
    __shared__ u32 part[256];
    int t = threadIdx.x;
    u32 loc[8]; u32 s = 0;
#pragma unroll
    for (int i = 0; i < 8; i++) { loc[i] = deg[t * 8 + i]; s += loc[i]; }
    part[t] = s; __syncthreads();
    for (int off = 1; off < 256; off <<= 1) {
        u32 vprev = (t >= off) ? part[t - off] : 0u;
        __syncthreads();
        part[t] += vprev;
        __syncthreads();
    }
    u32 run = (t == 0) ? 0u : part[t - 1];
    if (t == 0) rowptr[0] = 0u;
#pragma unroll
    for (int i = 0; i < 8; i++) { run += loc[i]; rowptr[t * 8 + i + 1] = run; }
}

__global__ __launch_bounds__(256) void emit_k(const u32* __restrict__ A, const u32* __restrict__ rowptr,
                                              u32* __restrict__ colidx, u32* __restrict__ cntv) {
    int r = blockIdx.x, tid = threadIdx.x;
    int lane = tid & 63, wid = tid >> 6;
    __shared__ u32 wsum[4];
    u32 base = rowptr[r];
    u32 cb = 0;
    for (int c0 = 0; c0 < NN; c0 += 256) {
        int c = c0 + tid;
        u32 a = A[r * NN + c];
        bool p = (a != 0u);
        u64 bal = __ballot(p);
        u32 rankw = (u32)__popcll(bal & ((1ull << lane) - 1ull));
        if (lane == 0) wsum[wid] = (u32)__popcll(bal);
        __syncthreads();
        u32 woff = 0;
#pragma unroll
        for (int w2 = 0; w2 < 4; w2++) if (w2 < wid) woff += wsum[w2];
        u32 tot = wsum[0] + wsum[1] + wsum[2] + wsum[3];
        if (p) { u32 pos = base + cb + woff + rankw; colidx[pos] = (u32)c; cntv[pos] = a; }
        cb += tot;
        __syncthreads();
    }
}

// ---------------- weight fragment conversion ----------------
// per layer (16384 slots of bf16x8): q[0,2048) k[2048,4096) v[4096,6144)
// o[6144,8192) W1[8192,12288) W2[12288,16384)
__global__ __launch_bounds__(256) void wconv_k(const float* __restrict__ Wq, const float* __restrict__ Wk,
                                               const float* __restrict__ Wv, const float* __restrict__ Wo,
                                               const float* __restrict__ W1, const float* __restrict__ W2,
                                               us8* __restrict__ Wf) {
    int tid = blockIdx.x * 256 + threadIdx.x;   // 0..131071
    int layer = tid >> 14;
    int r = tid & 16383;
    const float* src;
    int s, NT, ld;
    if (r < 8192) {
        int reg = r >> 11;         // 0..3 : q,k,v,o
        s = r & 2047;
        NT = 8; ld = 128;
        const float* bases[4] = {Wq, Wk, Wv, Wo};
        src = bases[reg] + layer * 16384;
    } else if (r < 12288) {
        s = r - 8192;
        NT = 16; ld = 256;
        src = W1 + layer * 32768;
    } else {
        s = r - 12288;
        NT = 8; ld = 128;
        src = W2 + layer * 32768;
    }
    int lane = s & 63;
    int t = s >> 6;
    int nt = t % NT;
    int kt = t / NT;
    int col = nt * 16 + (lane & 15);
    int k0 = kt * 32 + (lane >> 4) * 8;
    us8 o;
#pragma unroll
    for (int j = 0; j < 8; j++) o[j] = f2bf(src[(k0 + j) * ld + col]);
    Wf[tid] = o;
}

// ---------------- input projection ----------------
__global__ __launch_bounds__(256) void h0_k(const float* __restrict__ X, const float* __restrict__ pe,
                                            const float* __restrict__ pW, const float* __restrict__ pb,
                                            const float* __restrict__ peW, const float* __restrict__ peb,
                                            float* __restrict__ h) {
    int idx = blockIdx.x * 256 + threadIdx.x;
    int r = idx >> 7, d = idx & 127;
    float acc = pb[d] + peb[d];
    acc += X[r * 4 + 0] * pW[0 * DD + d];
    acc += X[r * 4 + 1] * pW[1 * DD + d];
    acc += X[r * 4 + 2] * pW[2 * DD + d];
    acc += X[r * 4 + 3] * pW[3 * DD + d];
    acc += pe[r * 2 + 0] * peW[0 * DD + d];
    acc += pe[r * 2 + 1] * peW[1 * DD + d];
    h[idx] = acc;
}

// ---------------- stats finalize helper (device) ----------------
__device__ __forceinline__ void finalize_stats(const float* __restrict__ ps, const float* __restrict__ pss,
                                               const float* __restrict__ gamma, const float* __restrict__ beta,
                                               float* aS, float* cS, int tidx) {
    if (tidx < 128) {
        if (ps) {
            float s = 0.f, s2 = 0.f;
#pragma unroll 8
            for (int i = 0; i < 128; i++) { s += ps[i * 128 + tidx]; s2 += pss[i * 128 + tidx]; }
            float mean = s * (1.0f / NN);
            float var = s2 * (1.0f / NN) - mean * mean;
            float rstd = rsqrtf(var + BNEPS);
            float a = gamma[tidx] * rstd;
            aS[tidx] = a;
            cS[tidx] = beta[tidx] - mean * a;
        } else {
            aS[tidx] = 1.f;
            cS[tidx] = 0.f;
        }
    }
}

// ---------------- fused QKV (normalize-on-load, vsum partials) ----------------
// grid 128 blocks (16-row strips) x 256 threads (4 waves); wave covers 6 of 24 tiles
__global__ __launch_bounds__(256) void qkv_k(const float* __restrict__ t,
                                             const float* __restrict__ ps, const float* __restrict__ pss,
                                             const float* __restrict__ gamma, const float* __restrict__ beta,
                                             const bf16x8* __restrict__ Wfl,
                                             const float* __restrict__ bq, const float* __restrict__ bk,
                                             const float* __restrict__ bv,
                                             float* __restrict__ q, float* __restrict__ k, float* __restrict__ v,
                                             float* __restrict__ psv) {
    __shared__ float aS[128], cS[128];
    int tidx = threadIdx.x;
    finalize_stats(ps, pss, gamma, beta, aS, cS, tidx);
    __syncthreads();
    int strip = blockIdx.x;
    int m0 = strip * 16;
    int lane = tidx & 63, wv = tidx >> 6;
    int arow = m0 + (lane & 15);
    int k0b = (lane >> 4) * 8;
    bf16x8 af[4];
#pragma unroll
    for (int kt = 0; kt < 4; kt++) {
        int k0 = kt * 32 + k0b;
        const float* tp = t + arow * DD + k0;
        float4 v0 = *(const float4*)(tp);
        float4 v1 = *(const float4*)(tp + 4);
        float vals[8] = {v0.x, v0.y, v0.z, v0.w, v1.x, v1.y, v1.z, v1.w};
        bf16x8 f;
#pragma unroll
        for (int j = 0; j < 8; j++) f[j] = (short)f2bf(vals[j] * aS[k0 + j] + cS[k0 + j]);
        af[kt] = f;
    }
#pragma unroll
    for (int ti = 0; ti < 6; ti++) {
        int tile = wv * 6 + ti;
        int mat = tile >> 3, nt = tile & 7;
        const bf16x8* wb = Wfl + mat * 2048;
        f32x4 acc = {0.f, 0.f, 0.f, 0.f};
#pragma unroll
        for (int kt = 0; kt < 4; kt++)
            acc = __builtin_amdgcn_mfma_f32_16x16x32_bf16(af[kt], wb[(kt * 8 + nt) * 64 + lane], acc, 0, 0, 0);
        const float* bias = (mat == 0) ? bq : ((mat == 1) ? bk : bv);
        float* outp = (mat == 0) ? q : ((mat == 1) ? k : v);
        float scale = (mat == 0) ? 0.25f : 1.0f;
        int col = nt * 16 + (lane & 15);
        int r0 = m0 + (lane >> 4) * 4;
        float bb = bias[col];
        float vals[4];
#pragma unroll
        for (int j = 0; j < 4; j++) {
            vals[j] = (acc[j] + bb) * scale;
            outp[(r0 + j) * DD + col] = vals[j];
        }
        if (mat == 2) {
            float cs = vals[0] + vals[1] + vals[2] + vals[3];
            cs += __shfl_xor(cs, 16);
            cs += __shfl_xor(cs, 32);
            if (lane < 16) psv[strip * 128 + col] = cs;
        }
    }
}

// ---------------- attention (vsum finalized in LDS) ----------------
// vsum[h][d] = sum over rows [h*256,h*256+256) and cols {d, d+16, ..., d+112}
__global__ __launch_bounds__(256) void attn2_k(const float* __restrict__ q, const float* __restrict__ kb,
                                               const float* __restrict__ vb, const u32* __restrict__ rowptr,
                                               const u32* __restrict__ colidx, const u32* __restrict__ cntv,
                                               const float* __restrict__ psv, unsigned short* __restrict__ obb) {
    int tid = threadIdx.x;
    int bid = blockIdx.x;
    int hh = bid >> 7;                 // 128 blocks per head
    __shared__ float vred[16][17];
    __shared__ float vsS[16];
    {
        int d = tid & 15, part = tid >> 4;
        int strip = hh * 16 + part;
        float s = 0.f;
#pragma unroll
        for (int i = 0; i < 8; i++) s += psv[strip * 128 + i * 16 + d];
        vred[d][part] = s;
    }
    __syncthreads();
    if (tid < 16) {
        float s = 0.f;
#pragma unroll
        for (int i = 0; i < 16; i++) s += vred[tid][i];
        vsS[tid] = s;
    }
    __syncthreads();

    int lane = tid & 15;
    int gidx = bid * 16 + (tid >> 4);
    int nn = gidx & (NN - 1);
    const float* qr = q + hh * (NN * HDIM) + nn * HDIM;
    float qv[16];
    *(float4*)&qv[0]  = *(const float4*)(qr + 0);
    *(float4*)&qv[4]  = *(const float4*)(qr + 4);
    *(float4*)&qv[8]  = *(const float4*)(qr + 8);
    *(float4*)&qv[12] = *(const float4*)(qr + 12);
    int rs = (int)rowptr[nn], re = (int)rowptr[nn + 1];
    int deg = re - rs;

    float s[8];
    int mc[8];
    float lm = -1e30f;
#pragma unroll
    for (int ch = 0; ch < 8; ch++) {
        s[ch] = -1e30f; mc[ch] = 0;
        if (ch * 16 < deg) {
            int e = rs + ch * 16 + lane;
            if (e < re) {
                mc[ch] = (int)colidx[e];
                float c = (float)cntv[e];
                const float* kr = kb + hh * (NN * HDIM) + mc[ch] * HDIM;
                float kv[16];
                *(float4*)&kv[0]  = *(const float4*)(kr + 0);
                *(float4*)&kv[4]  = *(const float4*)(kr + 4);
                *(float4*)&kv[8]  = *(const float4*)(kr + 8);
                *(float4*)&kv[12] = *(const float4*)(kr + 12);
                float d = 0.f;
#pragma unroll
                for (int i = 0; i < 16; i++) d += qv[i] * kv[i];
                s[ch] = c * d;
            }
            lm = fmaxf(lm, s[ch]);
        }
    }
    for (int base = rs + 128; base < re; base += 16) {
        int e = base + lane;
        if (e < re) {
            int m2 = (int)colidx[e];
            float c = (float)cntv[e];
            const float* kr = kb + hh * (NN * HDIM) + m2 * HDIM;
            float d = 0.f;
#pragma unroll
            for (int i = 0; i < 16; i++) d += qv[i] * kr[i];
            lm = fmaxf(lm, c * d);
        }
    }
#pragma unroll
    for (int off = 1; off < 16; off <<= 1) lm = fmaxf(lm, __shfl_xor(lm, off));
    float rowmax = fmaxf(lm, 0.f);
    float em = __expf(-rowmax);

    float z = 0.f;
    float acc[16];
#pragma unroll
    for (int i = 0; i < 16; i++) acc[i] = 0.f;
#pragma unroll
    for (int ch = 0; ch < 8; ch++) {
        if (ch * 16 < deg) {
            int e = rs + ch * 16 + lane;
            if (e < re) {
                float w = __expf(s[ch] - rowmax);
                z += w;
                float coef = w - em;
                const float* vr = vb + hh * (NN * HDIM) + mc[ch] * HDIM;
                float vv[16];
                *(float4*)&vv[0]  = *(const float4*)(vr + 0);
                *(float4*)&vv[4]  = *(const float4*)(vr + 4);
                *(float4*)&vv[8]  = *(const float4*)(vr + 8);
                *(float4*)&vv[12] = *(const float4*)(vr + 12);
#pragma unroll
                for (int i = 0; i < 16; i++) acc[i] += coef * vv[i];
            }
        }
    }
    for (int base = rs + 128; base < re; base += 16) {
        int e = base + lane;
        if (e < re) {
            int m2 = (int)colidx[e];
            float c = (float)cntv[e];
            const float* kr = kb + hh * (NN * HDIM) + m2 * HDIM;
            float d = 0.f;
#pragma unroll
            for (int i = 0; i < 16; i++) d += qv[i] * kr[i];
            float w = __expf(c * d - rowmax);
            z += w;
            float coef = w - em;
            const float* vr = vb + hh * (NN * HDIM) + m2 * HDIM;
#pragma unroll
            for (int i = 0; i < 16; i++) acc[i] += coef * vr[i];
        }
    }
#pragma unroll
    for (int off = 1; off < 16; off <<= 1) {
        z += __shfl_xor(z, off);
#pragma unroll
        for (int i = 0; i < 16; i++) acc[i] += __shfl_xor(acc[i], off);
    }
    if (lane == 0) {
        float Z = z + (float)(NN - deg) * em;
        float inv = 1.f / Z;
        unsigned short* orow = obb + hh * (NN * HDIM) + nn * HDIM;
        us8 lo, hi;
#pragma unroll
        for (int i = 0; i < 8; i++) {
            lo[i] = f2bf((acc[i] + em * vsS[i]) * inv);
            hi[i] = f2bf((acc[i + 8] + em * vsS[i + 8]) * inv);
        }
        *(us8*)(orow + 0) = lo;
        *(us8*)(orow + 8) = hi;
    }
}

// ---------------- O-proj + residual(normalized prev) + stats partials ----------------
__global__ __launch_bounds__(256) void gemmO_k(const unsigned short* __restrict__ obb,
                                               const bf16x8* __restrict__ Wfo,
                                               const float* __restrict__ bo,
                                               const float* __restrict__ tprev,
                                               const float* __restrict__ ps, const float* __restrict__ pss,
                                               const float* __restrict__ gamma, const float* __restrict__ beta,
                                               float* __restrict__ t1,
                                               float* __restrict__ ps1, float* __restrict__ pss1) {
    __shared__ float aS[128], cS[128];
    int tidx = threadIdx.x;
    finalize_stats(ps, pss, gamma, beta, aS, cS, tidx);
    __syncthreads();
    int strip = blockIdx.x;
    int m0 = strip * 16;
    int lane = tidx & 63, wv = tidx >> 6;
    int arow = m0 + (lane & 15);
    int k0b = (lane >> 4) * 8;
    bf16x8 af[4];
#pragma unroll
    for (int kt = 0; kt < 4; kt++)
        af[kt] = *(const bf16x8*)(obb + arow * DD + kt * 32 + k0b);
#pragma unroll
    for (int ti = 0; ti < 2; ti++) {
        int nt = wv * 2 + ti;
        f32x4 acc = {0.f, 0.f, 0.f, 0.f};
#pragma unroll
        for (int kt = 0; kt < 4; kt++)
            acc = __builtin_amdgcn_mfma_f32_16x16x32_bf16(af[kt], Wfo[(kt * 8 + nt) * 64 + lane], acc, 0, 0, 0);
        int col = nt * 16 + (lane & 15);
        int r0 = m0 + (lane >> 4) * 4;
        float bb = bo[col];
        float a = aS[col], c = cS[col];
        float sum = 0.f, sumsq = 0.f;
#pragma unroll
        for (int j = 0; j < 4; j++) {
            float res = tprev[(r0 + j) * DD + col] * a + c;
            float v0 = acc[j] + bb + res;
            t1[(r0 + j) * DD + col] = v0;
            sum += v0; sumsq += v0 * v0;
        }
        sum += __shfl_xor(sum, 16);  sum += __shfl_xor(sum, 32);
        sumsq += __shfl_xor(sumsq, 16); sumsq += __shfl_xor(sumsq, 32);
        if (lane < 16) { ps1[strip * 128 + col] = sum; pss1[strip * 128 + col] = sumsq; }
    }
}

// ---------------- fused MLP: normalize(t1) -> W1/relu (LDS) -> W2 + residual + stats ----------------
// grid 128 x 256 (4 waves per 16-row strip)
__global__ __launch_bounds__(256) void mlp_k(const float* __restrict__ t1,
                                             const float* __restrict__ ps1, const float* __restrict__ pss1,
                                             const float* __restrict__ g1, const float* __restrict__ be1,
                                             const bf16x8* __restrict__ Wf1, const float* __restrict__ b1,
                                             const bf16x8* __restrict__ Wf2, const float* __restrict__ b2,
                                             float* __restrict__ t2,
                                             float* __restrict__ ps2, float* __restrict__ pss2) {
    __shared__ float aS[128], cS[128];
    __shared__ unsigned short midL[16][264];
    int tidx = threadIdx.x;
    finalize_stats(ps1, pss1, g1, be1, aS, cS, tidx);
    __syncthreads();
    int strip = blockIdx.x;
    int m0 = strip * 16;
    int lane = tidx & 63, wv = tidx >> 6;
    int lrow = lane & 15;
    int arow = m0 + lrow;
    int k0b = (lane >> 4) * 8;
    bf16x8 af[4];
#pragma unroll
    for (int kt = 0; kt < 4; kt++) {
        int k0 = kt * 32 + k0b;
        const float* tp = t1 + arow * DD + k0;
        float4 v0 = *(const float4*)(tp);
        float4 v1 = *(const float4*)(tp + 4);
        float vals[8] = {v0.x, v0.y, v0.z, v0.w, v1.x, v1.y, v1.z, v1.w};
        bf16x8 f;
#pragma unroll
        for (int j = 0; j < 8; j++) f[j] = (short)f2bf(vals[j] * aS[k0 + j] + cS[k0 + j]);
        af[kt] = f;
    }
    // W1: wave wv covers mid col tiles nt = wv*4 .. wv*4+3  (16 tiles, 256 cols)
#pragma unroll
    for (int ti = 0; ti < 4; ti++) {
        int nt = wv * 4 + ti;
        f32x4 acc = {0.f, 0.f, 0.f, 0.f};
#pragma unroll
        for (int kt = 0; kt < 4; kt++)
            acc = __builtin_amdgcn_mfma_f32_16x16x32_bf16(af[kt], Wf1[(kt * 16 + nt) * 64 + lane], acc, 0, 0, 0);
        int col = nt * 16 + (lane & 15);
        int r0l = (lane >> 4) * 4;
        float bb = b1[col];
#pragma unroll
        for (int j = 0; j < 4; j++)
            midL[r0l + j][col] = f2bf(fmaxf(acc[j] + bb, 0.f));
    }
    __syncthreads();
    // W2: K=256, A from LDS; wave wv covers out col tiles nt = wv*2, wv*2+1
    bf16x8 af2[8];
#pragma unroll
    for (int kt = 0; kt < 8; kt++)
        af2[kt] = *(const bf16x8*)(&midL[lrow][kt * 32 + k0b]);
#pragma unroll
    for (int ti = 0; ti < 2; ti++) {
        int nt = wv * 2 + ti;
        f32x4 acc = {0.f, 0.f, 0.f, 0.f};
#pragma unroll
        for (int kt = 0; kt < 8; kt++)
            acc = __builtin_amdgcn_mfma_f32_16x16x32_bf16(af2[kt], Wf2[(kt * 8 + nt) * 64 + lane], acc, 0, 0, 0);
        int col = nt * 16 + (lane & 15);
        int r0 = m0 + (lane >> 4) * 4;
        float bb = b2[col];
        float a = aS[col], c = cS[col];
        float sum = 0.f, sumsq = 0.f;
#pragma unroll
        for (int j = 0; j < 4; j++) {
            float res = t1[(r0 + j) * DD + col] * a + c;
            float v0 = acc[j] + bb + res;
            t2[(r0 + j) * DD + col] = v0;
            sum += v0; sumsq += v0 * v0;
        }
        sum += __shfl_xor(sum, 16);  sum += __shfl_xor(sum, 32);
        sumsq += __shfl_xor(sumsq, 16); sumsq += __shfl_xor(sumsq, 32);
        if (lane < 16) { ps2[strip * 128 + col] = sum; pss2[strip * 128 + col] = sumsq; }
    }
}

// ---------------- pooling (finalize last BN on the fly) + head ----------------
__global__ __launch_bounds__(128) void pool_k(const float* __restrict__ t, const float* __restrict__ ps,
                                              const float* __restrict__ pss, const float* __restrict__ gamma,
                                              const float* __restrict__ beta, const int* __restrict__ gid,
                                              float* __restrict__ pooled) {
    int g = blockIdx.x;
    int d = threadIdx.x;
    float s = 0.f, s2 = 0.f;
#pragma unroll 8
    for (int i = 0; i < 128; i++) { s += ps[i * 128 + d]; s2 += pss[i * 128 + d]; }
    float mean = s * (1.0f / NN);
    float var = s2 * (1.0f / NN) - mean * mean;
    float rstd = rsqrtf(var + BNEPS);
    float a = gamma[d] * rstd;
    float c = beta[d] - mean * a;
    int lo = 0, hi = NN;
    while (lo < hi) { int mid = (lo + hi) >> 1; if (gid[mid] < g) lo = mid + 1; else hi = mid; }
    int start = lo;
    lo = start; hi = NN;
    while (lo < hi) { int mid = (lo + hi) >> 1; if (gid[mid] <= g) lo = mid + 1; else hi = mid; }
    int end = lo;
    float acc = 0.f;
    for (int r = start; r < end; r++) acc += t[r * DD + d] * a + c;
    pooled[g * DD + d] = acc;
}

__global__ __launch_bounds__(256) void head_k(const float* __restrict__ pooled, const float* __restrict__ W1,
                                              const float* __restrict__ b1, const float* __restrict__ W2,
                                              const float* __restrict__ b2, float* __restrict__ out) {
    int g = blockIdx.x;
    __shared__ float p[128], midv[128];
    if (threadIdx.x < 128) p[threadIdx.x] = pooled[g * DD + threadIdx.x];
    __syncthreads();
    if (threadIdx.x < 128) {
        int d = threadIdx.x;
        float acc = b1[d];
        for (int k2 = 0; k2 < 128; k2++) acc += p[k2] * W1[k2 * 128 + d];
        midv[d] = fmaxf(acc, 0.f);
    }
    __syncthreads();
    if (threadIdx.x < 64) {
        int j = threadIdx.x;
        float acc = b2[j];
        for (int k2 = 0; k2 < 128; k2++) acc += midv[k2] * W2[k2 * 64 + j];
        out[g * 64 + j] = acc;
    }
}

// ---------------- host ----------------
extern "C" void kernel_launch(void* const* d_in, const int* in_sizes, int n_in,
                              void* d_out, int out_size, void* d_ws, size_t ws_size,
                              hipStream_t stream) {
    (void)n_in; (void)out_size; (void)ws_size;
    const float* X      = (const float*)d_in[0];
    const float* pos    = (const float*)d_in[1];
    const int*   ei     = (const int*)d_in[2];
    const int*   gid    = (const int*)d_in[3];
    const float* proj_W = (const float*)d_in[5];
    const float* proj_b = (const float*)d_in[6];
    const float* pe_W   = (const float*)d_in[7];
    const float* pe_b   = (const float*)d_in[8];
    const float* Wq     = (const float*)d_in[9];
    const float* bq     = (const float*)d_in[10];
    const float* Wk     = (const float*)d_in[11];
    const float* bk     = (const float*)d_in[12];
    const float* Wv     = (const float*)d_in[13];
    const float* bv     = (const float*)d_in[14];
    const float* Wo     = (const float*)d_in[15];
    const float* bo     = (const float*)d_in[16];
    const float* g1     = (const float*)d_in[17];
    const float* beta1  = (const float*)d_in[18];
    const float* W1     = (const float*)d_in[19];
    const float* b1     = (const float*)d_in[20];
    const float* W2     = (const float*)d_in[21];
    const float* b2     = (const float*)d_in[22];
    const float* g2     = (const float*)d_in[23];
    const float* beta2  = (const float*)d_in[24];
    const float* mW1    = (const float*)d_in[25];
    const float* mb1    = (const float*)d_in[26];
    const float* mW2    = (const float*)d_in[27];
    const float* mb2    = (const float*)d_in[28];
    float* out = (float*)d_out;

    int E = in_sizes[2] / 2;

    char* w = (char*)d_ws;
    u32*   Adense = (u32*)(w + 0);                         // 16 MB
    u32*   deg    = (u32*)(w + 16777216);
    u32*   rowptr = (u32*)(w + 16785408);
    u32*   colidx = (u32*)(w + 16793856);
    u32*   cntv   = (u32*)(w + 17056000);
    float* tA     = (float*)(w + 17318144);                // 1 MB
    float* tB     = (float*)(w + 18366720);                // 1 MB
    float* qb     = (float*)(w + 19415296);                // 1 MB
    float* kb     = (float*)(w + 20463872);                // 1 MB
    float* vb     = (float*)(w + 21512448);                // 1 MB
    unsigned short* obb = (unsigned short*)(w + 22561024); // 0.5 MB
    float* psA    = (float*)(w + 23085312);                // 64 KB
    float* pssA   = (float*)(w + 23150848);
    float* psB    = (float*)(w + 23216384);
    float* pssB   = (float*)(w + 23281920);
    float* psv    = (float*)(w + 23347456);
    float* pooled = (float*)(w + 23412992);
    bf16x8* Wf    = (bf16x8*)(w + 23421184);               // 2 MB

    // adjacency -> dedup'd CSR with counts.
    // NOTE: zero_k (not hipMemsetAsync) — ROCm dispatches large fills on an
    // internal blit queue that escapes stream graph capture; replays would
    // then accumulate counts in Adense (post-timing divergence in R5).
    zero_k<<<4096, 256, 0, stream>>>((uint4*)Adense);
    scatter_k<<<(E + 255) / 256, 256, 0, stream>>>(ei, Adense, E);
    count_k<<<NN, 256, 0, stream>>>(Adense, deg);
    scan_k<<<1, 256, 0, stream>>>(deg, rowptr);
    emit_k<<<NN, 256, 0, stream>>>(Adense, rowptr, colidx, cntv);

    // weight fragments (all layers, one launch)
    wconv_k<<<512, 256, 0, stream>>>(Wq, Wk, Wv, Wo, W1, W2, (us8*)Wf);

    // input projection -> tA (layer 0 input, no BN)
    h0_k<<<NN * DD / 256, 256, 0, stream>>>(X, pos, proj_W, proj_b, pe_W, pe_b, tA);

    for (int l = 0; l < LL; l++) {
        const bf16x8* Wfl = Wf + l * 16384;
        const float* psIn  = (l == 0) ? nullptr : psA;
        const float* pssIn = (l == 0) ? nullptr : pssA;
        const float* gIn   = (l == 0) ? nullptr : (g2 + (l - 1) * DD);
        const float* bIn   = (l == 0) ? nullptr : (beta2 + (l - 1) * DD);

        qkv_k<<<128, 256, 0, stream>>>(tA, psIn, pssIn, gIn, bIn, Wfl,
                                       bq + l * DD, bk + l * DD, bv + l * DD, qb, kb, vb, psv);
        attn2_k<<<HH * NN / 16, 256, 0, stream>>>(qb, kb, vb, rowptr, colidx, cntv, psv, obb);
        gemmO_k<<<128, 256, 0, stream>>>(obb, Wfl + 6144, bo + l * DD, tA, psIn, pssIn, gIn, bIn,
                                         tB, psB, pssB);
        mlp_k<<<128, 256, 0, stream>>>(tB, psB, pssB, g1 + l * DD, beta1 + l * DD,
                                       Wfl + 8192, b1 + l * 2 * DD, Wfl + 12288, b2 + l * DD,
                                       tA, psA, pssA);
    }

    pool_k<<<GG, 128, 0, stream>>>(tA, psA, pssA, g2 + 7 * DD, beta2 + 7 * DD, gid, pooled);
    head_k<<<GG, 256, 0, stream>>>(pooled, mW1, mb1, mW2, mb2, out);
}

// Round 7
// 336.665 us; speedup vs baseline: 2.8505x; 1.1937x over previous
//
#include <hip/hip_runtime.h>
#include <hip/hip_bf16.h>

#define NN 2048
#define DD 128
#define HH 8
#define HDIM 16
#define LL 8
#define GG 16
#define BNEPS 1e-5f

typedef unsigned int u32;
typedef unsigned long long u64;
typedef __attribute__((ext_vector_type(8))) short bf16x8;
typedef __attribute__((ext_vector_type(8))) unsigned short us8;
typedef __attribute__((ext_vector_type(4))) float f32x4;

__device__ __forceinline__ unsigned short f2bf(float f) {
    union { float f; u32 u; } v; v.f = f;
    u32 u = v.u;
    u32 r = (u + 0x7fffu + ((u >> 16) & 1u)) >> 16;
    return (unsigned short)r;
}

// ---------------- workspace zeroing (graph-capture-safe; replaces hipMemsetAsync) ----------------
__global__ __launch_bounds__(256) void zero_k(uint4* __restrict__ p) {
    p[blockIdx.x * 256 + threadIdx.x] = make_uint4(0u, 0u, 0u, 0u);
}

// ---------------- adjacency build ----------------
__global__ __launch_bounds__(256) void scatter_k(const int* __restrict__ ei, u32* __restrict__ A, int E) {
    int e = blockIdx.x * 256 + threadIdx.x;
    if (e < E) {
        int s = ei[e];
        int d = ei[E + e];
        atomicAdd(&A[s * NN + d], 1u);
    }
}

__global__ __launch_bounds__(256) void count_k(const u32* __restrict__ A, u32* __restrict__ deg) {
    int r = blockIdx.x, t = threadIdx.x;
    __shared__ u32 sb[256];
    u32 c = 0;
    for (int j = t; j < NN; j += 256) c += (A[r * NN + j] != 0u) ? 1u : 0u;
    sb[t] = c; __syncthreads();
    for (int off = 128; off; off >>= 1) { if (t < off) sb[t] += sb[t + off]; __syncthreads(); }
    if (t == 0) deg[r] = sb[0];
}

__global__ __launch_bounds__(256) void scan_k(const u32* __restrict__ deg, u32* __restrict__ rowptr) {
    __shared__ u32 part[256];
    int t = threadIdx.x;
    u32 loc[8]; u32 s = 0;
#pragma unroll
    for (int i = 0; i < 8; i++) { loc[i] = deg[t * 8 + i]; s += loc[i]; }
    part[t] = s; __syncthreads();
    for (int off = 1; off < 256; off <<= 1) {
        u32 vprev = (t >= off) ? part[t - off] : 0u;
        __syncthreads();
        part[t] += vprev;
        __syncthreads();
    }
    u32 run = (t == 0) ? 0u : part[t - 1];
    if (t == 0) rowptr[0] = 0u;
#pragma unroll
    for (int i = 0; i < 8; i++) { run += loc[i]; rowptr[t * 8 + i + 1] = run; }
}

__global__ __launch_bounds__(256) void emit_k(const u32* __restrict__ A, const u32* __restrict__ rowptr,
                                              u32* __restrict__ colidx, u32* __restrict__ cntv) {
    int r = blockIdx.x, tid = threadIdx.x;
    int lane = tid & 63, wid = tid >> 6;
    __shared__ u32 wsum[4];
    u32 base = rowptr[r];
    u32 cb = 0;
    for (int c0 = 0; c0 < NN; c0 += 256) {
        int c = c0 + tid;
        u32 a = A[r * NN + c];
        bool p = (a != 0u);
        u64 bal = __ballot(p);
        u32 rankw = (u32)__popcll(bal & ((1ull << lane) - 1ull));
        if (lane == 0) wsum[wid] = (u32)__popcll(bal);
        __syncthreads();
        u32 woff = 0;
#pragma unroll
        for (int w2 = 0; w2 < 4; w2++) if (w2 < wid) woff += wsum[w2];
        u32 tot = wsum[0] + wsum[1] + wsum[2] + wsum[3];
        if (p) { u32 pos = base + cb + woff + rankw; colidx[pos] = (u32)c; cntv[pos] = a; }
        cb += tot;
        __syncthreads();
    }
}

// ---------------- weight fragment conversion ----------------
// per layer (16384 slots of bf16x8): q[0,2048) k[2048,4096) v[4096,6144)
// o[6144,8192) W1[8192,12288) W2[12288,16384)
__global__ __launch_bounds__(256) void wconv_k(const float* __restrict__ Wq, const float* __restrict__ Wk,
                                               const float* __restrict__ Wv, const float* __restrict__ Wo,
                                               const float* __restrict__ W1, const float* __restrict__ W2,
                                               us8* __restrict__ Wf) {
    int tid = blockIdx.x * 256 + threadIdx.x;   // 0..131071
    int layer = tid >> 14;
    int r = tid & 16383;
    const float* src;
    int s, NT, ld;
    if (r < 8192) {
        int reg = r >> 11;         // 0..3 : q,k,v,o
        s = r & 2047;
        NT = 8; ld = 128;
        const float* bases[4] = {Wq, Wk, Wv, Wo};
        src = bases[reg] + layer * 16384;
    } else if (r < 12288) {
        s = r - 8192;
        NT = 16; ld = 256;
        src = W1 + layer * 32768;
    } else {
        s = r - 12288;
        NT = 8; ld = 128;
        src = W2 + layer * 32768;
    }
    int lane = s & 63;
    int t = s >> 6;
    int nt = t % NT;
    int kt = t / NT;
    int col = nt * 16 + (lane & 15);
    int k0 = kt * 32 + (lane >> 4) * 8;
    us8 o;
#pragma unroll
    for (int j = 0; j < 8; j++) o[j] = f2bf(src[(k0 + j) * ld + col]);
    Wf[tid] = o;
}

// ---------------- input projection ----------------
__global__ __launch_bounds__(256) void h0_k(const float* __restrict__ X, const float* __restrict__ pe,
                                            const float* __restrict__ pW, const float* __restrict__ pb,
                                            const float* __restrict__ peW, const float* __restrict__ peb,
                                            float* __restrict__ h) {
    int idx = blockIdx.x * 256 + threadIdx.x;
    int r = idx >> 7, d = idx & 127;
    float acc = pb[d] + peb[d];
    acc += X[r * 4 + 0] * pW[0 * DD + d];
    acc += X[r * 4 + 1] * pW[1 * DD + d];
    acc += X[r * 4 + 2] * pW[2 * DD + d];
    acc += X[r * 4 + 3] * pW[3 * DD + d];
    acc += pe[r * 2 + 0] * peW[0 * DD + d];
    acc += pe[r * 2 + 1] * peW[1 * DD + d];
    h[idx] = acc;
}

// ---------------- stats finalize, 256-thread parallel (2 threads per dim) ----------------
// sred must be float[512] LDS scratch. Result: aS[128], cS[128].
__device__ __forceinline__ void finalize_stats2(const float* __restrict__ ps, const float* __restrict__ pss,
                                                const float* __restrict__ gamma, const float* __restrict__ beta,
                                                float* aS, float* cS, float* sred, int tidx) {
    if (ps) {
        int d = tidx & 127, half = tidx >> 7;
        float s = 0.f, s2 = 0.f;
        const float* p0 = ps + half * 64 * 128 + d;
        const float* p1 = pss + half * 64 * 128 + d;
#pragma unroll 8
        for (int i = 0; i < 64; i++) { s += p0[i * 128]; s2 += p1[i * 128]; }
        sred[tidx] = s;
        sred[256 + tidx] = s2;
        __syncthreads();
        if (tidx < 128) {
            float st = sred[tidx] + sred[tidx + 128];
            float s2t = sred[256 + tidx] + sred[256 + tidx + 128];
            float mean = st * (1.0f / NN);
            float var = s2t * (1.0f / NN) - mean * mean;
            float rstd = rsqrtf(var + BNEPS);
            float a = gamma[tidx] * rstd;
            aS[tidx] = a;
            cS[tidx] = beta[tidx] - mean * a;
        }
    } else if (tidx < 128) {
        aS[tidx] = 1.f;
        cS[tidx] = 0.f;
    }
}

// ---------------- fused QKV (normalize-on-load, vsum partials) ----------------
// grid 128 blocks (16-row strips) x 256 threads (4 waves); wave covers 6 of 24 tiles
__global__ __launch_bounds__(256) void qkv_k(const float* __restrict__ t,
                                             const float* __restrict__ ps, const float* __restrict__ pss,
                                             const float* __restrict__ gamma, const float* __restrict__ beta,
                                             const bf16x8* __restrict__ Wfl,
                                             const float* __restrict__ bq, const float* __restrict__ bk,
                                             const float* __restrict__ bv,
                                             float* __restrict__ q, float* __restrict__ k, float* __restrict__ v,
                                             float* __restrict__ psv) {
    __shared__ float aS[128], cS[128], sred[512];
    int tidx = threadIdx.x;
    finalize_stats2(ps, pss, gamma, beta, aS, cS, sred, tidx);
    __syncthreads();
    int strip = blockIdx.x;
    int m0 = strip * 16;
    int lane = tidx & 63, wv = tidx >> 6;
    int arow = m0 + (lane & 15);
    int k0b = (lane >> 4) * 8;
    bf16x8 af[4];
#pragma unroll
    for (int kt = 0; kt < 4; kt++) {
        int k0 = kt * 32 + k0b;
        const float* tp = t + arow * DD + k0;
        float4 v0 = *(const float4*)(tp);
        float4 v1 = *(const float4*)(tp + 4);
        float vals[8] = {v0.x, v0.y, v0.z, v0.w, v1.x, v1.y, v1.z, v1.w};
        bf16x8 f;
#pragma unroll
        for (int j = 0; j < 8; j++) f[j] = (short)f2bf(vals[j] * aS[k0 + j] + cS[k0 + j]);
        af[kt] = f;
    }
#pragma unroll
    for (int ti = 0; ti < 6; ti++) {
        int tile = wv * 6 + ti;
        int mat = tile >> 3, nt = tile & 7;
        const bf16x8* wb = Wfl + mat * 2048;
        f32x4 acc = {0.f, 0.f, 0.f, 0.f};
#pragma unroll
        for (int kt = 0; kt < 4; kt++)
            acc = __builtin_amdgcn_mfma_f32_16x16x32_bf16(af[kt], wb[(kt * 8 + nt) * 64 + lane], acc, 0, 0, 0);
        const float* bias = (mat == 0) ? bq : ((mat == 1) ? bk : bv);
        float* outp = (mat == 0) ? q : ((mat == 1) ? k : v);
        float scale = (mat == 0) ? 0.25f : 1.0f;
        int col = nt * 16 + (lane & 15);
        int r0 = m0 + (lane >> 4) * 4;
        float bb = bias[col];
        float vals[4];
#pragma unroll
        for (int j = 0; j < 4; j++) {
            vals[j] = (acc[j] + bb) * scale;
            outp[(r0 + j) * DD + col] = vals[j];
        }
        if (mat == 2) {
            float cs = vals[0] + vals[1] + vals[2] + vals[3];
            cs += __shfl_xor(cs, 16);
            cs += __shfl_xor(cs, 32);
            if (lane < 16) psv[strip * 128 + col] = cs;
        }
    }
}

// ---------------- attention (vsum finalized in LDS) ----------------
// vsum[h][d] = sum over rows [h*256,h*256+256) and cols {d, d+16, ..., d+112}
__global__ __launch_bounds__(256) void attn2_k(const float* __restrict__ q, const float* __restrict__ kb,
                                               const float* __restrict__ vb, const u32* __restrict__ rowptr,
                                               const u32* __restrict__ colidx, const u32* __restrict__ cntv,
                                               const float* __restrict__ psv, unsigned short* __restrict__ obb) {
    int tid = threadIdx.x;
    int bid = blockIdx.x;
    int hh = bid >> 7;                 // 128 blocks per head
    __shared__ float vred[16][17];
    __shared__ float vsS[16];
    {
        int d = tid & 15, part = tid >> 4;
        int strip = hh * 16 + part;
        float s = 0.f;
#pragma unroll
        for (int i = 0; i < 8; i++) s += psv[strip * 128 + i * 16 + d];
        vred[d][part] = s;
    }
    __syncthreads();
    if (tid < 16) {
        float s = 0.f;
#pragma unroll
        for (int i = 0; i < 16; i++) s += vred[tid][i];
        vsS[tid] = s;
    }
    __syncthreads();

    int lane = tid & 15;
    int gidx = bid * 16 + (tid >> 4);
    int nn = gidx & (NN - 1);
    const float* qr = q + hh * (NN * HDIM) + nn * HDIM;
    float qv[16];
    *(float4*)&qv[0]  = *(const float4*)(qr + 0);
    *(float4*)&qv[4]  = *(const float4*)(qr + 4);
    *(float4*)&qv[8]  = *(const float4*)(qr + 8);
    *(float4*)&qv[12] = *(const float4*)(qr + 12);
    int rs = (int)rowptr[nn], re = (int)rowptr[nn + 1];
    int deg = re - rs;

    float s[8];
    int mc[8];
    float lm = -1e30f;
#pragma unroll
    for (int ch = 0; ch < 8; ch++) {
        s[ch] = -1e30f; mc[ch] = 0;
        if (ch * 16 < deg) {
            int e = rs + ch * 16 + lane;
            if (e < re) {
                mc[ch] = (int)colidx[e];
                float c = (float)cntv[e];
                const float* kr = kb + hh * (NN * HDIM) + mc[ch] * HDIM;
                float kv[16];
                *(float4*)&kv[0]  = *(const float4*)(kr + 0);
                *(float4*)&kv[4]  = *(const float4*)(kr + 4);
                *(float4*)&kv[8]  = *(const float4*)(kr + 8);
                *(float4*)&kv[12] = *(const float4*)(kr + 12);
                float d = 0.f;
#pragma unroll
                for (int i = 0; i < 16; i++) d += qv[i] * kv[i];
                s[ch] = c * d;
            }
            lm = fmaxf(lm, s[ch]);
        }
    }
    for (int base = rs + 128; base < re; base += 16) {
        int e = base + lane;
        if (e < re) {
            int m2 = (int)colidx[e];
            float c = (float)cntv[e];
            const float* kr = kb + hh * (NN * HDIM) + m2 * HDIM;
            float d = 0.f;
#pragma unroll
            for (int i = 0; i < 16; i++) d += qv[i] * kr[i];
            lm = fmaxf(lm, c * d);
        }
    }
#pragma unroll
    for (int off = 1; off < 16; off <<= 1) lm = fmaxf(lm, __shfl_xor(lm, off));
    float rowmax = fmaxf(lm, 0.f);
    float em = __expf(-rowmax);

    float z = 0.f;
    float acc[16];
#pragma unroll
    for (int i = 0; i < 16; i++) acc[i] = 0.f;
#pragma unroll
    for (int ch = 0; ch < 8; ch++) {
        if (ch * 16 < deg) {
            int e = rs + ch * 16 + lane;
            if (e < re) {
                float w = __expf(s[ch] - rowmax);
                z += w;
                float coef = w - em;
                const float* vr = vb + hh * (NN * HDIM) + mc[ch] * HDIM;
                float vv[16];
                *(float4*)&vv[0]  = *(const float4*)(vr + 0);
                *(float4*)&vv[4]  = *(const float4*)(vr + 4);
                *(float4*)&vv[8]  = *(const float4*)(vr + 8);
                *(float4*)&vv[12] = *(const float4*)(vr + 12);
#pragma unroll
                for (int i = 0; i < 16; i++) acc[i] += coef * vv[i];
            }
        }
    }
    for (int base = rs + 128; base < re; base += 16) {
        int e = base + lane;
        if (e < re) {
            int m2 = (int)colidx[e];
            float c = (float)cntv[e];
            const float* kr = kb + hh * (NN * HDIM) + m2 * HDIM;
            float d = 0.f;
#pragma unroll
            for (int i = 0; i < 16; i++) d += qv[i] * kr[i];
            float w = __expf(c * d - rowmax);
            z += w;
            float coef = w - em;
            const float* vr = vb + hh * (NN * HDIM) + m2 * HDIM;
#pragma unroll
            for (int i = 0; i < 16; i++) acc[i] += coef * vr[i];
        }
    }
#pragma unroll
    for (int off = 1; off < 16; off <<= 1) {
        z += __shfl_xor(z, off);
#pragma unroll
        for (int i = 0; i < 16; i++) acc[i] += __shfl_xor(acc[i], off);
    }
    if (lane == 0) {
        float Z = z + (float)(NN - deg) * em;
        float inv = 1.f / Z;
        unsigned short* orow = obb + hh * (NN * HDIM) + nn * HDIM;
        us8 lo, hi;
#pragma unroll
        for (int i = 0; i < 8; i++) {
            lo[i] = f2bf((acc[i] + em * vsS[i]) * inv);
            hi[i] = f2bf((acc[i + 8] + em * vsS[i + 8]) * inv);
        }
        *(us8*)(orow + 0) = lo;
        *(us8*)(orow + 8) = hi;
    }
}

// ---------------- O-proj + residual(normalized prev) + stats partials ----------------
__global__ __launch_bounds__(256) void gemmO_k(const unsigned short* __restrict__ obb,
                                               const bf16x8* __restrict__ Wfo,
                                               const float* __restrict__ bo,
                                               const float* __restrict__ tprev,
                                               const float* __restrict__ ps, const float* __restrict__ pss,
                                               const float* __restrict__ gamma, const float* __restrict__ beta,
                                               float* __restrict__ t1,
                                               float* __restrict__ ps1, float* __restrict__ pss1) {
    __shared__ float aS[128], cS[128], sred[512];
    int tidx = threadIdx.x;
    finalize_stats2(ps, pss, gamma, beta, aS, cS, sred, tidx);
    __syncthreads();
    int strip = blockIdx.x;
    int m0 = strip * 16;
    int lane = tidx & 63, wv = tidx >> 6;
    int arow = m0 + (lane & 15);
    int k0b = (lane >> 4) * 8;
    bf16x8 af[4];
#pragma unroll
    for (int kt = 0; kt < 4; kt++)
        af[kt] = *(const bf16x8*)(obb + arow * DD + kt * 32 + k0b);
#pragma unroll
    for (int ti = 0; ti < 2; ti++) {
        int nt = wv * 2 + ti;
        f32x4 acc = {0.f, 0.f, 0.f, 0.f};
#pragma unroll
        for (int kt = 0; kt < 4; kt++)
            acc = __builtin_amdgcn_mfma_f32_16x16x32_bf16(af[kt], Wfo[(kt * 8 + nt) * 64 + lane], acc, 0, 0, 0);
        int col = nt * 16 + (lane & 15);
        int r0 = m0 + (lane >> 4) * 4;
        float bb = bo[col];
        float a = aS[col], c = cS[col];
        float sum = 0.f, sumsq = 0.f;
#pragma unroll
        for (int j = 0; j < 4; j++) {
            float res = tprev[(r0 + j) * DD + col] * a + c;
            float v0 = acc[j] + bb + res;
            t1[(r0 + j) * DD + col] = v0;
            sum += v0; sumsq += v0 * v0;
        }
        sum += __shfl_xor(sum, 16);  sum += __shfl_xor(sum, 32);
        sumsq += __shfl_xor(sumsq, 16); sumsq += __shfl_xor(sumsq, 32);
        if (lane < 16) { ps1[strip * 128 + col] = sum; pss1[strip * 128 + col] = sumsq; }
    }
}

// ---------------- fused MLP: normalize(t1) -> W1/relu (LDS) -> W2 + residual + stats ----------------
// grid 128 x 256 (4 waves per 16-row strip)
__global__ __launch_bounds__(256) void mlp_k(const float* __restrict__ t1,
                                             const float* __restrict__ ps1, const float* __restrict__ pss1,
                                             const float* __restrict__ g1, const float* __restrict__ be1,
                                             const bf16x8* __restrict__ Wf1, const float* __restrict__ b1,
                                             const bf16x8* __restrict__ Wf2, const float* __restrict__ b2,
                                             float* __restrict__ t2,
                                             float* __restrict__ ps2, float* __restrict__ pss2) {
    __shared__ float aS[128], cS[128], sred[512];
    __shared__ unsigned short midL[16][264];
    int tidx = threadIdx.x;
    finalize_stats2(ps1, pss1, g1, be1, aS, cS, sred, tidx);
    __syncthreads();
    int strip = blockIdx.x;
    int m0 = strip * 16;
    int lane = tidx & 63, wv = tidx >> 6;
    int lrow = lane & 15;
    int arow = m0 + lrow;
    int k0b = (lane >> 4) * 8;
    bf16x8 af[4];
#pragma unroll
    for (int kt = 0; kt < 4; kt++) {
        int k0 = kt * 32 + k0b;
        const float* tp = t1 + arow * DD + k0;
        float4 v0 = *(const float4*)(tp);
        float4 v1 = *(const float4*)(tp + 4);
        float vals[8] = {v0.x, v0.y, v0.z, v0.w, v1.x, v1.y, v1.z, v1.w};
        bf16x8 f;
#pragma unroll
        for (int j = 0; j < 8; j++) f[j] = (short)f2bf(vals[j] * aS[k0 + j] + cS[k0 + j]);
        af[kt] = f;
    }
    // W1: wave wv covers mid col tiles nt = wv*4 .. wv*4+3  (16 tiles, 256 cols)
#pragma unroll
    for (int ti = 0; ti < 4; ti++) {
        int nt = wv * 4 + ti;
        f32x4 acc = {0.f, 0.f, 0.f, 0.f};
#pragma unroll
        for (int kt = 0; kt < 4; kt++)
            acc = __builtin_amdgcn_mfma_f32_16x16x32_bf16(af[kt], Wf1[(kt * 16 + nt) * 64 + lane], acc, 0, 0, 0);
        int col = nt * 16 + (lane & 15);
        int r0l = (lane >> 4) * 4;
        float bb = b1[col];
#pragma unroll
        for (int j = 0; j < 4; j++)
            midL[r0l + j][col] = f2bf(fmaxf(acc[j] + bb, 0.f));
    }
    __syncthreads();
    // W2: K=256, A from LDS; wave wv covers out col tiles nt = wv*2, wv*2+1
    bf16x8 af2[8];
#pragma unroll
    for (int kt = 0; kt < 8; kt++)
        af2[kt] = *(const bf16x8*)(&midL[lrow][kt * 32 + k0b]);
#pragma unroll
    for (int ti = 0; ti < 2; ti++) {
        int nt = wv * 2 + ti;
        f32x4 acc = {0.f, 0.f, 0.f, 0.f};
#pragma unroll
        for (int kt = 0; kt < 8; kt++)
            acc = __builtin_amdgcn_mfma_f32_16x16x32_bf16(af2[kt], Wf2[(kt * 8 + nt) * 64 + lane], acc, 0, 0, 0);
        int col = nt * 16 + (lane & 15);
        int r0 = m0 + (lane >> 4) * 4;
        float bb = b2[col];
        float a = aS[col], c = cS[col];
        float sum = 0.f, sumsq = 0.f;
#pragma unroll
        for (int j = 0; j < 4; j++) {
            float res = t1[(r0 + j) * DD + col] * a + c;
            float v0 = acc[j] + bb + res;
            t2[(r0 + j) * DD + col] = v0;
            sum += v0; sumsq += v0 * v0;
        }
        sum += __shfl_xor(sum, 16);  sum += __shfl_xor(sum, 32);
        sumsq += __shfl_xor(sumsq, 16); sumsq += __shfl_xor(sumsq, 32);
        if (lane < 16) { ps2[strip * 128 + col] = sum; pss2[strip * 128 + col] = sumsq; }
    }
}

// ---------------- parallel pooling: (graph, chunk) partials ----------------
// grid (GG, 8) x 128 threads; partial[(g*8+c)*128 + d]
__global__ __launch_bounds__(128) void poolpart_k(const float* __restrict__ t, const float* __restrict__ ps,
                                                  const float* __restrict__ pss, const float* __restrict__ gamma,
                                                  const float* __restrict__ beta, const int* __restrict__ gid,
                                                  float* __restrict__ poolp) {
    int g = blockIdx.x;
    int ch = blockIdx.y;
    int d = threadIdx.x;
    float s = 0.f, s2 = 0.f;
#pragma unroll 8
    for (int i = 0; i < 128; i++) { s += ps[i * 128 + d]; s2 += pss[i * 128 + d]; }
    float mean = s * (1.0f / NN);
    float var = s2 * (1.0f / NN) - mean * mean;
    float rstd = rsqrtf(var + BNEPS);
    float a = gamma[d] * rstd;
    float c = beta[d] - mean * a;
    int lo = 0, hi = NN;
    while (lo < hi) { int mid = (lo + hi) >> 1; if (gid[mid] < g) lo = mid + 1; else hi = mid; }
    int start = lo;
    lo = start; hi = NN;
    while (lo < hi) { int mid = (lo + hi) >> 1; if (gid[mid] <= g) lo = mid + 1; else hi = mid; }
    int end = lo;
    float acc = 0.f;
    for (int r = start + ch; r < end; r += 8) acc += t[r * DD + d] * a + c;
    poolp[(g * 8 + ch) * DD + d] = acc;
}

__global__ __launch_bounds__(256) void head_k(const float* __restrict__ poolp, const float* __restrict__ W1,
                                              const float* __restrict__ b1, const float* __restrict__ W2,
                                              const float* __restrict__ b2, float* __restrict__ out) {
    int g = blockIdx.x;
    __shared__ float p[128], midv[128];
    if (threadIdx.x < 128) {
        float s = 0.f;
#pragma unroll
        for (int c = 0; c < 8; c++) s += poolp[(g * 8 + c) * DD + threadIdx.x];
        p[threadIdx.x] = s;
    }
    __syncthreads();
    if (threadIdx.x < 128) {
        int d = threadIdx.x;
        float acc = b1[d];
        for (int k2 = 0; k2 < 128; k2++) acc += p[k2] * W1[k2 * 128 + d];
        midv[d] = fmaxf(acc, 0.f);
    }
    __syncthreads();
    if (threadIdx.x < 64) {
        int j = threadIdx.x;
        float acc = b2[j];
        for (int k2 = 0; k2 < 128; k2++) acc += midv[k2] * W2[k2 * 64 + j];
        out[g * 64 + j] = acc;
    }
}

// ---------------- host ----------------
extern "C" void kernel_launch(void* const* d_in, const int* in_sizes, int n_in,
                              void* d_out, int out_size, void* d_ws, size_t ws_size,
                              hipStream_t stream) {
    (void)n_in; (void)out_size; (void)ws_size;
    const float* X      = (const float*)d_in[0];
    const float* pos    = (const float*)d_in[1];
    const int*   ei     = (const int*)d_in[2];
    const int*   gid    = (const int*)d_in[3];
    const float* proj_W = (const float*)d_in[5];
    const float* proj_b = (const float*)d_in[6];
    const float* pe_W   = (const float*)d_in[7];
    const float* pe_b   = (const float*)d_in[8];
    const float* Wq     = (const float*)d_in[9];
    const float* bq     = (const float*)d_in[10];
    const float* Wk     = (const float*)d_in[11];
    const float* bk     = (const float*)d_in[12];
    const float* Wv     = (const float*)d_in[13];
    const float* bv     = (const float*)d_in[14];
    const float* Wo     = (const float*)d_in[15];
    const float* bo     = (const float*)d_in[16];
    const float* g1     = (const float*)d_in[17];
    const float* beta1  = (const float*)d_in[18];
    const float* W1     = (const float*)d_in[19];
    const float* b1     = (const float*)d_in[20];
    const float* W2     = (const float*)d_in[21];
    const float* b2     = (const float*)d_in[22];
    const float* g2     = (const float*)d_in[23];
    const float* beta2  = (const float*)d_in[24];
    const float* mW1    = (const float*)d_in[25];
    const float* mb1    = (const float*)d_in[26];
    const float* mW2    = (const float*)d_in[27];
    const float* mb2    = (const float*)d_in[28];
    float* out = (float*)d_out;

    int E = in_sizes[2] / 2;

    char* w = (char*)d_ws;
    u32*   Adense = (u32*)(w + 0);                         // 16 MB
    u32*   deg    = (u32*)(w + 16777216);
    u32*   rowptr = (u32*)(w + 16785408);
    u32*   colidx = (u32*)(w + 16793856);
    u32*   cntv   = (u32*)(w + 17056000);
    float* tA     = (float*)(w + 17318144);                // 1 MB
    float* tB     = (float*)(w + 18366720);                // 1 MB
    float* qb     = (float*)(w + 19415296);                // 1 MB
    float* kb     = (float*)(w + 20463872);                // 1 MB
    float* vb     = (float*)(w + 21512448);                // 1 MB
    unsigned short* obb = (unsigned short*)(w + 22561024); // 0.5 MB
    float* psA    = (float*)(w + 23085312);                // 64 KB
    float* pssA   = (float*)(w + 23150848);
    float* psB    = (float*)(w + 23216384);
    float* pssB   = (float*)(w + 23281920);
    float* psv    = (float*)(w + 23347456);
    bf16x8* Wf    = (bf16x8*)(w + 23421184);               // 2 MB
    float* poolp  = (float*)(w + 25518336);                // 64 KB (16*8*128 floats)

    // adjacency -> dedup'd CSR with counts (zero_k: graph-capture-safe fill)
    zero_k<<<4096, 256, 0, stream>>>((uint4*)Adense);
    scatter_k<<<(E + 255) / 256, 256, 0, stream>>>(ei, Adense, E);
    count_k<<<NN, 256, 0, stream>>>(Adense, deg);
    scan_k<<<1, 256, 0, stream>>>(deg, rowptr);
    emit_k<<<NN, 256, 0, stream>>>(Adense, rowptr, colidx, cntv);

    // weight fragments (all layers, one launch)
    wconv_k<<<512, 256, 0, stream>>>(Wq, Wk, Wv, Wo, W1, W2, (us8*)Wf);

    // input projection -> tA (layer 0 input, no BN)
    h0_k<<<NN * DD / 256, 256, 0, stream>>>(X, pos, proj_W, proj_b, pe_W, pe_b, tA);

    for (int l = 0; l < LL; l++) {
        const bf16x8* Wfl = Wf + l * 16384;
        const float* psIn  = (l == 0) ? nullptr : psA;
        const float* pssIn = (l == 0) ? nullptr : pssA;
        const float* gIn   = (l == 0) ? nullptr : (g2 + (l - 1) * DD);
        const float* bIn   = (l == 0) ? nullptr : (beta2 + (l - 1) * DD);

        qkv_k<<<128, 256, 0, stream>>>(tA, psIn, pssIn, gIn, bIn, Wfl,
                                       bq + l * DD, bk + l * DD, bv + l * DD, qb, kb, vb, psv);
        attn2_k<<<HH * NN / 16, 256, 0, stream>>>(qb, kb, vb, rowptr, colidx, cntv, psv, obb);
        gemmO_k<<<128, 256, 0, stream>>>(obb, Wfl + 6144, bo + l * DD, tA, psIn, pssIn, gIn, bIn,
                                         tB, psB, pssB);
        mlp_k<<<128, 256, 0, stream>>>(tB, psB, pssB, g1 + l * DD, beta1 + l * DD,
                                       Wfl + 8192, b1 + l * 2 * DD, Wfl + 12288, b2 + l * DD,
                                       tA, psA, pssA);
    }

    poolpart_k<<<dim3(GG, 8), 128, 0, stream>>>(tA, psA, pssA, g2 + 7 * DD, beta2 + 7 * DD, gid, poolp);
    head_k<<<GG, 256, 0, stream>>>(poolp, mW1, mb1, mW2, mb2, out);
}